// Round 1
// baseline (6536.111 us; speedup 1.0000x reference)
//
#include <hip/hip_runtime.h>
#include <math.h>

#define NN 10000
#define NE 160000
#define DND 256
#define DER 64
#define DEA 32
#define DEC 96
#define DAC 352

__device__ __forceinline__ float sigm(float x){ return 1.0f/(1.0f + expf(-x)); }

// ---------------- s2[i] = src[src[i]] (reference quirk) ----------------
__global__ void k_s2(const int* __restrict__ src, int* __restrict__ s2){
    int i = blockIdx.x*256 + threadIdx.x;
    if (i < NE) s2[i] = src[src[i]];
}

// ---------------- shared GEMM pass: acc += A_tile @ W_tile ----------------
// Tile: 64 rows x 64 cols, BK=16, 256 threads, 4x4 per thread.
// As padded to 68 floats/row so float4 reads are 16B-aligned & conflict-light.
template<typename FA>
__device__ __forceinline__ void gemm_pass(float (&acc)[4][4], FA&& loadA,
                                          const float* __restrict__ W,
                                          int K, int Nc, int col0,
                                          float (*As)[68], float (*Ws)[64])
{
    const int tid = threadIdx.x;
    const int tx = tid & 15, ty = tid >> 4;
    for (int k0 = 0; k0 < K; k0 += 16){
        #pragma unroll
        for (int l = 0; l < 4; ++l){
            int idx = tid + (l << 8);
            int r = idx >> 4, kk = idx & 15;
            As[kk][r] = loadA(r, k0 + kk);
        }
        #pragma unroll
        for (int l = 0; l < 4; ++l){
            int idx = tid + (l << 8);
            int kk = idx >> 6, c = idx & 63;
            int gk = k0 + kk, gc = col0 + c;
            Ws[kk][c] = (gk < K && gc < Nc) ? W[(size_t)gk*Nc + gc] : 0.f;
        }
        __syncthreads();
        #pragma unroll
        for (int k = 0; k < 16; ++k){
            float4 av = *reinterpret_cast<const float4*>(&As[k][ty<<2]);
            float4 wv = *reinterpret_cast<const float4*>(&Ws[k][tx<<2]);
            float a[4] = {av.x, av.y, av.z, av.w};
            float w[4] = {wv.x, wv.y, wv.z, wv.w};
            #pragma unroll
            for (int i=0;i<4;++i)
                #pragma unroll
                for (int j=0;j<4;++j)
                    acc[i][j] = fmaf(a[i], w[j], acc[i][j]);
        }
        __syncthreads();
    }
}

// ---------------- generic GEMM: C = act(A@W + b) ----------------
template<int ACT>   // 0=none, 1=relu
__global__ void k_gemm(const float* __restrict__ A, const float* __restrict__ W,
                       const float* __restrict__ bias, float* __restrict__ C,
                       int M, int K, int Nc)
{
    __shared__ float As[16][68];
    __shared__ float Ws[16][64];
    const int tid = threadIdx.x;
    const int tx = tid & 15, ty = tid >> 4;
    const int row0 = blockIdx.y << 6, col0 = blockIdx.x << 6;
    float acc[4][4] = {};
    auto loadA = [&](int r, int gk) -> float {
        int gr = row0 + r;
        return (gr < M && gk < K) ? A[(size_t)gr*K + gk] : 0.f;
    };
    gemm_pass(acc, loadA, W, K, Nc, col0, As, Ws);
    #pragma unroll
    for (int i=0;i<4;++i){
        int gr = row0 + (ty<<2) + i;
        if (gr >= M) continue;
        #pragma unroll
        for (int j=0;j<4;++j){
            int gc = col0 + (tx<<2) + j;
            if (gc >= Nc) continue;
            float v = acc[i][j] + bias[gc];
            if (ACT == 1) v = fmaxf(v, 0.f);
            C[(size_t)gr*Nc + gc] = v;
        }
    }
}

// ---------------- msg GEMM + sigmoid + atomic scatter into agg ----------------
// msg_in row e = [nf[s2[e]] (256) | er[e] (64) | ea[e] (32)], W=mlp1_w [352x352]
__global__ void k_msg_scatter(const float* __restrict__ nf, const float* __restrict__ er,
                              const float* __restrict__ ea, const int* __restrict__ s2,
                              const int* __restrict__ dst,
                              const float* __restrict__ W, const float* __restrict__ bias,
                              float* __restrict__ agg)
{
    __shared__ float As[16][68];
    __shared__ float Ws[16][64];
    __shared__ int ss[64], dd[64];
    const int tid = threadIdx.x;
    const int tx = tid & 15, ty = tid >> 4;
    const int e0 = blockIdx.y << 6, col0 = blockIdx.x << 6;
    if (tid < 64){ ss[tid] = s2[e0+tid]; dd[tid] = dst[e0+tid]; }
    __syncthreads();
    float acc[4][4] = {};
    auto loadA = [&](int r, int k) -> float {
        int e = e0 + r;
        if (k < DND)      return nf[(size_t)ss[r]*DND + k];
        if (k < DND+DER)  return er[(size_t)e*DER + (k - DND)];
        return ea[(size_t)e*DEA + (k - DND - DER)];
    };
    gemm_pass(acc, loadA, W, DAC, DAC, col0, As, Ws);
    #pragma unroll
    for (int i=0;i<4;++i){
        int r = (ty<<2)+i;
        #pragma unroll
        for (int j=0;j<4;++j){
            int gc = col0 + (tx<<2) + j;
            if (gc < DAC){
                float v = sigm(acc[i][j] + bias[gc]);
                atomicAdd(&agg[(size_t)dd[r]*DAC + gc], v);
            }
        }
    }
}

// ---------------- node update: nfu = sigm(nf@Wls + m@Wln + bls + bln) + nf ----------------
__global__ void k_node_update(const float* __restrict__ nf, const float* __restrict__ m,
                              const float* __restrict__ Wls, const float* __restrict__ bls,
                              const float* __restrict__ Wln, const float* __restrict__ bln,
                              float* __restrict__ nfu)
{
    __shared__ float As[16][68];
    __shared__ float Ws[16][64];
    const int tid = threadIdx.x;
    const int tx = tid & 15, ty = tid >> 4;
    const int row0 = blockIdx.y << 6, col0 = blockIdx.x << 6;
    float acc1[4][4] = {}, acc2[4][4] = {};
    auto loadA1 = [&](int r, int gk) -> float {
        int gr = row0 + r;
        return (gr < NN) ? nf[(size_t)gr*DND + gk] : 0.f;
    };
    gemm_pass(acc1, loadA1, Wls, DND, DND, col0, As, Ws);
    auto loadA2 = [&](int r, int gk) -> float {
        int gr = row0 + r;
        return (gr < NN) ? m[(size_t)gr*DND + gk] : 0.f;
    };
    gemm_pass(acc2, loadA2, Wln, DND, DND, col0, As, Ws);
    #pragma unroll
    for (int i=0;i<4;++i){
        int gr = row0 + (ty<<2) + i;
        if (gr >= NN) continue;
        #pragma unroll
        for (int j=0;j<4;++j){
            int gc = col0 + (tx<<2) + j;
            float base = nf[(size_t)gr*DND + gc];
            float v = sigm(acc1[i][j] + acc2[i][j] + bls[gc] + bln[gc]) + base;
            nfu[(size_t)gr*DND + gc] = v;
        }
    }
}

// ---------------- h2 = sigm(s_in@em1 + be1) + sigm(t_in@mlp1 + b1) ----------------
__global__ void k_h2(const float* __restrict__ nfu, const float* __restrict__ er,
                     const float* __restrict__ ea, const int* __restrict__ src,
                     const int* __restrict__ dst,
                     const float* __restrict__ W1, const float* __restrict__ b1,
                     const float* __restrict__ W2, const float* __restrict__ b2,
                     float* __restrict__ out, int eBase)
{
    __shared__ float As[16][68];
    __shared__ float Ws[16][64];
    __shared__ int ss[64], dd[64];
    const int tid = threadIdx.x;
    const int tx = tid & 15, ty = tid >> 4;
    const int e0 = eBase + (blockIdx.y << 6), col0 = blockIdx.x << 6;
    if (tid < 64){ ss[tid] = src[e0+tid]; dd[tid] = dst[e0+tid]; }
    __syncthreads();
    float acc1[4][4] = {}, acc2[4][4] = {};
    auto loadS = [&](int r, int k) -> float {
        int e = e0 + r;
        if (k < DND)      return nfu[(size_t)ss[r]*DND + k];
        if (k < DND+DER)  return er[(size_t)e*DER + (k - DND)];
        return ea[(size_t)e*DEA + (k - DND - DER)];
    };
    gemm_pass(acc1, loadS, W1, DAC, DAC, col0, As, Ws);
    auto loadT = [&](int r, int k) -> float {
        int e = e0 + r;
        if (k < DND)      return nfu[(size_t)dd[r]*DND + k];
        if (k < DND+DER)  return er[(size_t)e*DER + (k - DND)];
        return ea[(size_t)e*DEA + (k - DND - DER)];
    };
    gemm_pass(acc2, loadT, W2, DAC, DAC, col0, As, Ws);
    #pragma unroll
    for (int i=0;i<4;++i){
        int rl = (blockIdx.y << 6) + (ty<<2) + i;   // row within chunk
        #pragma unroll
        for (int j=0;j<4;++j){
            int gc = col0 + (tx<<2) + j;
            if (gc < DAC){
                float v = sigm(acc1[i][j] + b1[gc]) + sigm(acc2[i][j] + b2[gc]);
                out[(size_t)rl*DAC + gc] = v;
            }
        }
    }
}

extern "C" void kernel_launch(void* const* d_in, const int* in_sizes, int n_in,
                              void* d_out, int out_size, void* d_ws, size_t ws_size,
                              hipStream_t stream)
{
    const float* NF  = (const float*)d_in[0];
    const float* ERD = (const float*)d_in[1];
    const float* EAD = (const float*)d_in[2];
    const int*   EIX = (const int*)d_in[3];
    const int* src = EIX; const int* dst = EIX + NE;
    const float* W1   = (const float*)d_in[4];  const float* B1   = (const float*)d_in[5];
    const float* W20  = (const float*)d_in[6];  const float* B20  = (const float*)d_in[7];
    const float* W21  = (const float*)d_in[8];  const float* B21  = (const float*)d_in[9];
    const float* W22  = (const float*)d_in[10]; const float* B22  = (const float*)d_in[11];
    const float* W23  = (const float*)d_in[12]; const float* B23  = (const float*)d_in[13];
    const float* WLS  = (const float*)d_in[14]; const float* BLS  = (const float*)d_in[15];
    const float* WLN  = (const float*)d_in[16]; const float* BLN  = (const float*)d_in[17];
    const float* WE1  = (const float*)d_in[18]; const float* BE1  = (const float*)d_in[19];
    const float* WE20 = (const float*)d_in[20]; const float* BE20 = (const float*)d_in[21];
    const float* WE21 = (const float*)d_in[22]; const float* BE21 = (const float*)d_in[23];
    const float* WE22 = (const float*)d_in[24]; const float* BE22 = (const float*)d_in[25];
    const float* WE23 = (const float*)d_in[26]; const float* BE23 = (const float*)d_in[27];

    float* ws  = (float*)d_ws;
    int*   s2  = (int*)d_ws;                       // [NE] ints
    float* agg = ws + NE;                          // [NN*352]
    float* h0  = agg + (size_t)NN*DAC;             // [NN*208]
    float* h1  = h0  + (size_t)NN*208;             // [NN*64]
    float* h2n = h1  + (size_t)NN*64;              // [NN*128]
    float* mm  = h2n + (size_t)NN*128;             // [NN*256]
    float* nfu = (float*)d_out;                    // output 0 [NN*256]
    float* efu = nfu + (size_t)NN*DND;             // output 1 [NE*96]

    // ---- node phase ----
    k_s2<<<dim3((NE+255)/256), 256, 0, stream>>>(src, s2);
    hipMemsetAsync(agg, 0, sizeof(float)*(size_t)NN*DAC, stream);
    k_msg_scatter<<<dim3(6, NE/64), 256, 0, stream>>>(NF, ERD, EAD, s2, dst, W1, B1, agg);
    k_gemm<1><<<dim3(4, 157), 256, 0, stream>>>(agg, W20, B20, h0,  NN, DAC, 208);
    k_gemm<1><<<dim3(1, 157), 256, 0, stream>>>(h0,  W21, B21, h1,  NN, 208, 64);
    k_gemm<1><<<dim3(2, 157), 256, 0, stream>>>(h1,  W22, B22, h2n, NN, 64, 128);
    k_gemm<0><<<dim3(4, 157), 256, 0, stream>>>(h2n, W23, B23, mm,  NN, 128, 256);
    k_node_update<<<dim3(4, 157), 256, 0, stream>>>(NF, mm, WLS, BLS, WLN, BLN, nfu);

    // ---- edge phase (chunked to fit workspace; node buffers are dead now) ----
    size_t wsFloats = ws_size / sizeof(float);
    const size_t perEdge = DAC + 188 + 24 + 48;    // 612 floats/edge
    size_t ce = wsFloats / perEdge;
    if (ce > NE) ce = NE;
    ce &= ~(size_t)63;
    int chunkE = (int)ce; if (chunkE < 64) chunkE = 64;

    float* h2e = ws;                               // [chunkE*352]
    float* e0b = h2e + (size_t)chunkE*DAC;         // [chunkE*188]
    float* e1b = e0b + (size_t)chunkE*188;         // [chunkE*24]
    float* e2b = e1b + (size_t)chunkE*24;          // [chunkE*48]

    for (int eb = 0; eb < NE; eb += chunkE){
        int cur = (NE - eb < chunkE) ? (NE - eb) : chunkE;
        int rt = cur / 64;
        k_h2<<<dim3(6, rt), 256, 0, stream>>>(nfu, ERD, EAD, src, dst,
                                              WE1, BE1, W1, B1, h2e, eb);
        k_gemm<1><<<dim3(3, rt), 256, 0, stream>>>(h2e, WE20, BE20, e0b, cur, DAC, 188);
        k_gemm<1><<<dim3(1, rt), 256, 0, stream>>>(e0b, WE21, BE21, e1b, cur, 188, 24);
        k_gemm<1><<<dim3(1, rt), 256, 0, stream>>>(e1b, WE22, BE22, e2b, cur, 24, 48);
        k_gemm<0><<<dim3(2, rt), 256, 0, stream>>>(e2b, WE23, BE23,
                                                   efu + (size_t)eb*DEC, cur, 48, 96);
    }
}

// Round 2
// 857.559 us; speedup vs baseline: 7.6218x; 7.6218x over previous
//
#include <hip/hip_runtime.h>
#include <math.h>

#define NN 10000
#define NE 160000
#define DND 256
#define DER 64
#define DEA 32
#define DEC 96
#define DAC 352

typedef __attribute__((ext_vector_type(4))) float f32x4;
typedef __attribute__((ext_vector_type(8))) short bf16x8;

__device__ __forceinline__ float sigm(float x){ return 1.0f/(1.0f+expf(-x)); }
__device__ __forceinline__ short f2b(float x){
    union { float f; unsigned u; } v; v.f = x;
    unsigned r = v.u + 0x7FFFu + ((v.u >> 16) & 1u);
    return (short)(r >> 16);
}

// ---------------- s2[i] = src[src[i]] ----------------
__global__ void k_s2(const int* __restrict__ src, int* __restrict__ s2){
    int i = blockIdx.x*256 + threadIdx.x;
    if (i < NE) s2[i] = src[src[i]];
}
// ---------------- f32 -> bf16 ----------------
__global__ void k_cvt(const float* __restrict__ in, short* __restrict__ out, int n){
    int i = blockIdx.x*256 + threadIdx.x;
    int stride = gridDim.x*256;
    for (; i < n; i += stride) out[i] = f2b(in[i]);
}
// ---------------- ec16[e][0:96] = [er|ea] bf16 ----------------
__global__ void k_ec(const float* __restrict__ er, const float* __restrict__ ea,
                     short* __restrict__ ec){
    int i = blockIdx.x*256 + threadIdx.x;
    int stride = gridDim.x*256;
    const int n = NE*DEC;
    for (; i < n; i += stride){
        int e = i / DEC, c = i - e*DEC;
        float v = (c < DER) ? er[(size_t)e*DER + c] : ea[(size_t)e*DEA + (c-DER)];
        ec[i] = f2b(v);
    }
}
// ---------------- Wt[n][k] = bf16(W[k][n]), zero-padded to ldW ----------------
__global__ void k_wt(const float* __restrict__ W, short* __restrict__ Wt,
                     int K, int N, int ldW){
    int i = blockIdx.x*256 + threadIdx.x;
    int total = N*ldW;
    if (i >= total) return;
    int n = i / ldW, k = i - n*ldW;
    Wt[i] = (k < K) ? f2b(W[(size_t)k*N + n]) : (short)0;
}

// ---------------- MFMA helpers ----------------
__device__ __forceinline__ void stageB(short (*Bs)[40], const short* __restrict__ Wt,
                                       int col0, int N, int K, int ldW, int k0, int tid){
    int c = tid>>2, ks = tid&3, k = k0 + ks*8;
    bf16x8 v = {0,0,0,0,0,0,0,0};
    int gc = col0 + c;
    if (gc < N && k < K) v = *(const bf16x8*)&Wt[(size_t)gc*ldW + k];
    *(bf16x8*)&Bs[c][ks*8] = v;
}

__device__ __forceinline__ void mfma_step(const short (*As)[40], const short (*Bs)[40],
                                          int wm, int wn, int lane,
                                          f32x4& a00, f32x4& a01, f32x4& a10, f32x4& a11){
    const int kofs = (lane>>4)*8, lr = lane & 15;
    bf16x8 A0 = *(const bf16x8*)&As[wm*32 + lr][kofs];
    bf16x8 A1 = *(const bf16x8*)&As[wm*32 + 16 + lr][kofs];
    bf16x8 B0 = *(const bf16x8*)&Bs[wn*32 + lr][kofs];
    bf16x8 B1 = *(const bf16x8*)&Bs[wn*32 + 16 + lr][kofs];
    a00 = __builtin_amdgcn_mfma_f32_16x16x32_bf16(A0, B0, a00, 0, 0, 0);
    a01 = __builtin_amdgcn_mfma_f32_16x16x32_bf16(A0, B1, a01, 0, 0, 0);
    a10 = __builtin_amdgcn_mfma_f32_16x16x32_bf16(A1, B0, a10, 0, 0, 0);
    a11 = __builtin_amdgcn_mfma_f32_16x16x32_bf16(A1, B1, a11, 0, 0, 0);
}

// gather K-loop over [nf16[idx[r]] | ec16[e]] @ Wt  (K = 352 fixed)
__device__ __forceinline__ void gemm_gather(const short* __restrict__ nftab,
    const short* __restrict__ ec16, const int* idx, int e0,
    const short* __restrict__ Wt, int col0, int tid, int lane, int wm, int wn,
    short (*As)[40], short (*Bs)[40],
    f32x4& a00, f32x4& a01, f32x4& a10, f32x4& a11)
{
    for (int k0 = 0; k0 < DAC; k0 += 32){
        {
            int r = tid>>2, ks = tid&3, k = k0 + ks*8;
            bf16x8 v;
            if (k < DND) v = *(const bf16x8*)&nftab[(size_t)idx[r]*DND + k];
            else         v = *(const bf16x8*)&ec16[(size_t)(e0+r)*DEC + (k-DND)];
            *(bf16x8*)&As[r][ks*8] = v;
        }
        stageB(Bs, Wt, col0, DAC, DAC, DAC, k0, tid);
        __syncthreads();
        mfma_step(As, Bs, wm, wn, lane, a00, a01, a10, a11);
        __syncthreads();
    }
}

// direct K-loop, K = 256 (node matrices)
__device__ __forceinline__ void gemm_direct256(const short* __restrict__ A, int row0,
    const short* __restrict__ Wt, int col0, int tid, int lane, int wm, int wn,
    short (*As)[40], short (*Bs)[40],
    f32x4& a00, f32x4& a01, f32x4& a10, f32x4& a11)
{
    for (int k0 = 0; k0 < DND; k0 += 32){
        {
            int r = tid>>2, ks = tid&3, k = k0 + ks*8;
            bf16x8 v = {0,0,0,0,0,0,0,0};
            int gr = row0 + r;
            if (gr < NN) v = *(const bf16x8*)&A[(size_t)gr*DND + k];
            *(bf16x8*)&As[r][ks*8] = v;
        }
        stageB(Bs, Wt, col0, DND, DND, DND, k0, tid);
        __syncthreads();
        mfma_step(As, Bs, wm, wn, lane, a00, a01, a10, a11);
        __syncthreads();
    }
}

// ---------------- generic C = act(A@Wt^T + b) ----------------
template<int ACT, bool F32OUT>   // ACT: 0 none, 1 relu
__global__ __launch_bounds__(256) void k_mm(const short* __restrict__ A,
                      const short* __restrict__ Wt, const float* __restrict__ bias,
                      void* __restrict__ Cv,
                      int M, int K, int N, int ldA, int ldW, int ldC)
{
    __shared__ short As[64][40];
    __shared__ short Bs[64][40];
    const int tid = threadIdx.x, lane = tid & 63, wave = tid >> 6;
    const int wm = wave >> 1, wn = wave & 1;
    const int row0 = blockIdx.y << 6, col0 = blockIdx.x << 6;
    f32x4 a00={0,0,0,0}, a01={0,0,0,0}, a10={0,0,0,0}, a11={0,0,0,0};
    for (int k0 = 0; k0 < K; k0 += 32){
        {
            int r = tid>>2, ks = tid&3, k = k0 + ks*8;
            bf16x8 v = {0,0,0,0,0,0,0,0};
            int gr = row0 + r;
            if (gr < M && k < K) v = *(const bf16x8*)&A[(size_t)gr*ldA + k];
            *(bf16x8*)&As[r][ks*8] = v;
        }
        stageB(Bs, Wt, col0, N, K, ldW, k0, tid);
        __syncthreads();
        mfma_step(As, Bs, wm, wn, lane, a00, a01, a10, a11);
        __syncthreads();
    }
    const int lr = lane & 15, lq = lane >> 4;
    f32x4 accs[2][2] = {{a00,a01},{a10,a11}};
    #pragma unroll
    for (int i = 0; i < 2; ++i)
      #pragma unroll
      for (int j = 0; j < 2; ++j){
        int col = col0 + wn*32 + j*16 + lr;
        if (col >= ldC) continue;
        bool valid = col < N;
        float bs = valid ? bias[col] : 0.f;
        #pragma unroll
        for (int q = 0; q < 4; ++q){
            int row = row0 + wm*32 + i*16 + lq*4 + q;
            if (row >= M) continue;
            float v = valid ? (accs[i][j][q] + bs) : 0.f;
            if (ACT == 1) v = fmaxf(v, 0.f);
            if (F32OUT) ((float*)Cv)[(size_t)row*ldC + col] = v;
            else        ((short*)Cv)[(size_t)row*ldC + col] = f2b(v);
        }
      }
}

// ---------------- msg: sigm([nf16[s2]|ec]@mlp1 + b) scatter-> agg ----------------
__global__ __launch_bounds__(256) void k_msg(const short* __restrict__ nf16,
                       const short* __restrict__ ec16,
                       const int* __restrict__ s2, const int* __restrict__ dst,
                       const short* __restrict__ Wt, const float* __restrict__ bias,
                       float* __restrict__ agg)
{
    __shared__ short As[64][40];
    __shared__ short Bs[64][40];
    __shared__ int ss[64], dd[64];
    const int tid = threadIdx.x, lane = tid & 63, wave = tid >> 6;
    const int wm = wave >> 1, wn = wave & 1;
    const int e0 = blockIdx.y << 6, col0 = blockIdx.x << 6;
    if (tid < 64){ ss[tid] = s2[e0+tid]; dd[tid] = dst[e0+tid]; }
    __syncthreads();
    f32x4 a00={0,0,0,0}, a01={0,0,0,0}, a10={0,0,0,0}, a11={0,0,0,0};
    gemm_gather(nf16, ec16, ss, e0, Wt, col0, tid, lane, wm, wn, As, Bs, a00,a01,a10,a11);
    const int lr = lane & 15, lq = lane >> 4;
    f32x4 accs[2][2] = {{a00,a01},{a10,a11}};
    #pragma unroll
    for (int i = 0; i < 2; ++i)
      #pragma unroll
      for (int j = 0; j < 2; ++j){
        int col = col0 + wn*32 + j*16 + lr;
        if (col >= DAC) continue;
        float bs = bias[col];
        #pragma unroll
        for (int q = 0; q < 4; ++q){
            int rl = wm*32 + i*16 + lq*4 + q;
            atomicAdd(&agg[(size_t)dd[rl]*DAC + col], sigm(accs[i][j][q] + bs));
        }
      }
}

// ---------------- h2 = sigm(s@em1+be1)+sigm(t@mlp1+b1) -> bf16 ----------------
__global__ __launch_bounds__(256) void k_h2m(const short* __restrict__ nfu16,
                       const short* __restrict__ ec16,
                       const int* __restrict__ src, const int* __restrict__ dst,
                       const short* __restrict__ W1t, const float* __restrict__ b1,
                       const short* __restrict__ W2t, const float* __restrict__ b2,
                       short* __restrict__ h2)
{
    __shared__ short As[64][40];
    __shared__ short Bs[64][40];
    __shared__ int ss[64], dd[64];
    const int tid = threadIdx.x, lane = tid & 63, wave = tid >> 6;
    const int wm = wave >> 1, wn = wave & 1;
    const int e0 = blockIdx.y << 6, col0 = blockIdx.x << 6;
    if (tid < 64){ ss[tid] = src[e0+tid]; dd[tid] = dst[e0+tid]; }
    __syncthreads();
    f32x4 s00={0,0,0,0}, s01={0,0,0,0}, s10={0,0,0,0}, s11={0,0,0,0};
    f32x4 t00={0,0,0,0}, t01={0,0,0,0}, t10={0,0,0,0}, t11={0,0,0,0};
    gemm_gather(nfu16, ec16, ss, e0, W1t, col0, tid, lane, wm, wn, As, Bs, s00,s01,s10,s11);
    gemm_gather(nfu16, ec16, dd, e0, W2t, col0, tid, lane, wm, wn, As, Bs, t00,t01,t10,t11);
    const int lr = lane & 15, lq = lane >> 4;
    f32x4 sa[2][2] = {{s00,s01},{s10,s11}};
    f32x4 ta[2][2] = {{t00,t01},{t10,t11}};
    #pragma unroll
    for (int i = 0; i < 2; ++i)
      #pragma unroll
      for (int j = 0; j < 2; ++j){
        int col = col0 + wn*32 + j*16 + lr;
        if (col >= DAC) continue;
        float c1 = b1[col], c2 = b2[col];
        #pragma unroll
        for (int q = 0; q < 4; ++q){
            int e = e0 + wm*32 + i*16 + lq*4 + q;
            float v = sigm(sa[i][j][q] + c1) + sigm(ta[i][j][q] + c2);
            h2[(size_t)e*DAC + col] = f2b(v);
        }
      }
}

// ---------------- node update ----------------
__global__ __launch_bounds__(256) void k_nodeup(const short* __restrict__ nf16,
                       const short* __restrict__ m16,
                       const short* __restrict__ Wlst, const short* __restrict__ Wlnt,
                       const float* __restrict__ bls, const float* __restrict__ bln,
                       const float* __restrict__ nf, float* __restrict__ nfu,
                       short* __restrict__ nfu16)
{
    __shared__ short As[64][40];
    __shared__ short Bs[64][40];
    const int tid = threadIdx.x, lane = tid & 63, wave = tid >> 6;
    const int wm = wave >> 1, wn = wave & 1;
    const int row0 = blockIdx.y << 6, col0 = blockIdx.x << 6;
    f32x4 s00={0,0,0,0}, s01={0,0,0,0}, s10={0,0,0,0}, s11={0,0,0,0};
    f32x4 t00={0,0,0,0}, t01={0,0,0,0}, t10={0,0,0,0}, t11={0,0,0,0};
    gemm_direct256(nf16, row0, Wlst, col0, tid, lane, wm, wn, As, Bs, s00,s01,s10,s11);
    gemm_direct256(m16,  row0, Wlnt, col0, tid, lane, wm, wn, As, Bs, t00,t01,t10,t11);
    const int lr = lane & 15, lq = lane >> 4;
    f32x4 sa[2][2] = {{s00,s01},{s10,s11}};
    f32x4 ta[2][2] = {{t00,t01},{t10,t11}};
    #pragma unroll
    for (int i = 0; i < 2; ++i)
      #pragma unroll
      for (int j = 0; j < 2; ++j){
        int col = col0 + wn*32 + j*16 + lr;
        float bb = bls[col] + bln[col];
        #pragma unroll
        for (int q = 0; q < 4; ++q){
            int row = row0 + wm*32 + i*16 + lq*4 + q;
            if (row >= NN) continue;
            float v = sigm(sa[i][j][q] + ta[i][j][q] + bb) + nf[(size_t)row*DND + col];
            nfu[(size_t)row*DND + col] = v;
            nfu16[(size_t)row*DND + col] = f2b(v);
        }
      }
}

extern "C" void kernel_launch(void* const* d_in, const int* in_sizes, int n_in,
                              void* d_out, int out_size, void* d_ws, size_t ws_size,
                              hipStream_t stream)
{
    const float* NF  = (const float*)d_in[0];
    const float* ERD = (const float*)d_in[1];
    const float* EAD = (const float*)d_in[2];
    const int*   EIX = (const int*)d_in[3];
    const int* src = EIX; const int* dst = EIX + NE;
    const float* W1   = (const float*)d_in[4];  const float* B1   = (const float*)d_in[5];
    const float* W20  = (const float*)d_in[6];  const float* B20  = (const float*)d_in[7];
    const float* W21  = (const float*)d_in[8];  const float* B21  = (const float*)d_in[9];
    const float* W22  = (const float*)d_in[10]; const float* B22  = (const float*)d_in[11];
    const float* W23  = (const float*)d_in[12]; const float* B23  = (const float*)d_in[13];
    const float* WLS  = (const float*)d_in[14]; const float* BLS  = (const float*)d_in[15];
    const float* WLN  = (const float*)d_in[16]; const float* BLN  = (const float*)d_in[17];
    const float* WE1  = (const float*)d_in[18]; const float* BE1  = (const float*)d_in[19];
    const float* WE20 = (const float*)d_in[20]; const float* BE20 = (const float*)d_in[21];
    const float* WE21 = (const float*)d_in[22]; const float* BE21 = (const float*)d_in[23];
    const float* WE22 = (const float*)d_in[24]; const float* BE22 = (const float*)d_in[25];
    const float* WE23 = (const float*)d_in[26]; const float* BE23 = (const float*)d_in[27];

    float* nfu = (float*)d_out;
    float* efu = nfu + (size_t)NN*DND;

    char* p = (char*)d_ws;
    auto alloc = [&](size_t bytes)->char*{ char* q = p; p += (bytes + 255) & ~(size_t)255; return q; };
    int*   s2    = (int*)  alloc((size_t)NE*4);
    short* nf16  = (short*)alloc((size_t)NN*DND*2);
    short* ec16  = (short*)alloc((size_t)NE*DEC*2);
    float* agg   = (float*)alloc((size_t)NN*DAC*4);
    short* agg16 = (short*)alloc((size_t)NN*DAC*2);
    short* h0    = (short*)alloc((size_t)NN*208*2);
    short* h1    = (short*)alloc((size_t)NN*64*2);
    short* h2n   = (short*)alloc((size_t)NN*128*2);
    short* m16   = (short*)alloc((size_t)NN*DND*2);
    short* nfu16 = (short*)alloc((size_t)NN*DND*2);
    short* h2e   = (short*)alloc((size_t)NE*DAC*2);
    short* e0b   = (short*)alloc((size_t)NE*192*2);
    short* e1b   = (short*)alloc((size_t)NE*24*2);
    short* e2b   = (short*)alloc((size_t)NE*48*2);
    short* W1t   = (short*)alloc(352*352*2);
    short* WE1t  = (short*)alloc(352*352*2);
    short* W20t  = (short*)alloc(208*352*2);
    short* W21t  = (short*)alloc(64*208*2);
    short* W22t  = (short*)alloc(128*64*2);
    short* W23t  = (short*)alloc(256*128*2);
    short* WLSt  = (short*)alloc(256*256*2);
    short* WLNt  = (short*)alloc(256*256*2);
    short* WE20t = (short*)alloc(188*352*2);
    short* WE21t = (short*)alloc(24*192*2);
    short* WE22t = (short*)alloc(48*24*2);
    short* WE23t = (short*)alloc(96*48*2);

    // ---- converts ----
    k_s2 <<<dim3((NE+255)/256), 256, 0, stream>>>(src, s2);
    k_cvt<<<dim3(2048), 256, 0, stream>>>(NF, nf16, NN*DND);
    k_ec <<<dim3(2048), 256, 0, stream>>>(ERD, EAD, ec16);
    auto wt = [&](const float* W, short* Wt, int K, int N, int ldW){
        int total = N*ldW;
        k_wt<<<dim3((total+255)/256), 256, 0, stream>>>(W, Wt, K, N, ldW);
    };
    wt(W1,   W1t,  352, 352, 352);
    wt(WE1,  WE1t, 352, 352, 352);
    wt(W20,  W20t, 352, 208, 352);
    wt(W21,  W21t, 208, 64,  208);
    wt(W22,  W22t, 64,  128, 64);
    wt(W23,  W23t, 128, 256, 128);
    wt(WLS,  WLSt, 256, 256, 256);
    wt(WLN,  WLNt, 256, 256, 256);
    wt(WE20, WE20t, 352, 188, 352);
    wt(WE21, WE21t, 188, 24,  192);
    wt(WE22, WE22t, 24,  48,  24);
    wt(WE23, WE23t, 48,  96,  48);

    // ---- node phase ----
    hipMemsetAsync(agg, 0, sizeof(float)*(size_t)NN*DAC, stream);
    k_msg<<<dim3(6, NE/64), 256, 0, stream>>>(nf16, ec16, s2, dst, W1t, B1, agg);
    k_cvt<<<dim3(2048), 256, 0, stream>>>(agg, agg16, NN*DAC);
    k_mm<1,false><<<dim3(4,157), 256, 0, stream>>>(agg16, W20t, B20, h0,  NN, 352, 208, 352, 352, 208);
    k_mm<1,false><<<dim3(1,157), 256, 0, stream>>>(h0,   W21t, B21, h1,  NN, 208, 64,  208, 208, 64);
    k_mm<1,false><<<dim3(2,157), 256, 0, stream>>>(h1,   W22t, B22, h2n, NN, 64,  128, 64,  64,  128);
    k_mm<0,false><<<dim3(4,157), 256, 0, stream>>>(h2n,  W23t, B23, m16, NN, 128, 256, 128, 128, 256);
    k_nodeup<<<dim3(4,157), 256, 0, stream>>>(nf16, m16, WLSt, WLNt, BLS, BLN, NF, nfu, nfu16);

    // ---- edge phase ----
    k_h2m<<<dim3(6, NE/64), 256, 0, stream>>>(nfu16, ec16, src, dst, WE1t, BE1, W1t, B1, h2e);
    k_mm<1,false><<<dim3(3, NE/64), 256, 0, stream>>>(h2e, WE20t, BE20, e0b, NE, 352, 188, 352, 352, 192);
    k_mm<1,false><<<dim3(1, NE/64), 256, 0, stream>>>(e0b, WE21t, BE21, e1b, NE, 188, 24,  192, 192, 24);
    k_mm<1,false><<<dim3(1, NE/64), 256, 0, stream>>>(e1b, WE22t, BE22, e2b, NE, 24,  48,  24,  24,  48);
    k_mm<0,true ><<<dim3(2, NE/64), 256, 0, stream>>>(e2b, WE23t, BE23, efu, NE, 48,  96,  48,  48,  96);
}

// Round 6
// 749.168 us; speedup vs baseline: 8.7245x; 1.1447x over previous
//
#include <hip/hip_runtime.h>
#include <math.h>

#define NN 10000
#define NE 160000
#define DND 256
#define DER 64
#define DEA 32
#define DEC 96
#define DAC 352

typedef __attribute__((ext_vector_type(4))) float f32x4;
typedef __attribute__((ext_vector_type(8))) short bf16x8;

__device__ __forceinline__ float sigm(float x){ return 1.0f/(1.0f+expf(-x)); }
__device__ __forceinline__ short f2b(float x){
    union { float f; unsigned u; } v; v.f = x;
    unsigned r = v.u + 0x7FFFu + ((v.u >> 16) & 1u);
    return (short)(r >> 16);
}

// ---------------- s2[i] = src[src[i]] (reference quirk) ----------------
__global__ void k_s2(const int* __restrict__ src, int* __restrict__ s2){
    int i = blockIdx.x*256 + threadIdx.x;
    if (i < NE) s2[i] = src[src[i]];
}

// ---------------- fused prep: nf16 + ec16 ----------------
__global__ void k_prep(const float* __restrict__ nf, const float* __restrict__ er,
                       const float* __restrict__ ea,
                       short* __restrict__ nf16, short* __restrict__ ec16){
    const int n1 = NN*DND, n2 = NE*DEC;
    int i = blockIdx.x*256 + threadIdx.x;
    int stride = gridDim.x*256;
    for (; i < n1 + n2; i += stride){
        if (i < n1) nf16[i] = f2b(nf[i]);
        else {
            int t = i - n1;
            int e = t / DEC, c = t - e*DEC;
            float v = (c < DER) ? er[(size_t)e*DER + c] : ea[(size_t)e*DEA + (c-DER)];
            ec16[t] = f2b(v);
        }
    }
}

// ---------------- f32 -> bf16 ----------------
__global__ void k_cvt(const float* __restrict__ in, short* __restrict__ out, int n){
    int i = blockIdx.x*256 + threadIdx.x;
    int stride = gridDim.x*256;
    for (; i < n; i += stride) out[i] = f2b(in[i]);
}

// ---------------- all weight transposes in one launch ----------------
struct WtJob { const float* W; long long dstOff; int K, N, ld, total; };
struct WtJobs { WtJob j[14]; int grand; };
__global__ void k_wtall(WtJobs jobs, short* __restrict__ pool){
    int i = blockIdx.x*256 + threadIdx.x;
    int stride = gridDim.x*256;
    for (; i < jobs.grand; i += stride){
        int t = i, jj = 0;
        while (t >= jobs.j[jj].total){ t -= jobs.j[jj].total; ++jj; }
        const WtJob J = jobs.j[jj];
        int n = t / J.ld, k = t - n*J.ld;
        pool[J.dstOff + t] = (k < J.K) ? f2b(J.W[(size_t)k*J.N + n]) : (short)0;
    }
}

// ---------------- MFMA helpers ----------------
__device__ __forceinline__ void stageB(short (*Bs)[40], const short* __restrict__ Wt,
                                       int col0, int N, int K, int ldW, int k0, int tid){
    int c = tid>>2, ks = tid&3, k = k0 + ks*8;
    bf16x8 v = {0,0,0,0,0,0,0,0};
    int gc = col0 + c;
    if (gc < N && k < K) v = *(const bf16x8*)&Wt[(size_t)gc*ldW + k];
    *(bf16x8*)&Bs[c][ks*8] = v;
}

__device__ __forceinline__ void mfma_step(const short (*As)[40], const short (*Bs)[40],
                                          int wm, int wn, int lane,
                                          f32x4& a00, f32x4& a01, f32x4& a10, f32x4& a11){
    const int kofs = (lane>>4)*8, lr = lane & 15;
    bf16x8 A0 = *(const bf16x8*)&As[wm*32 + lr][kofs];
    bf16x8 A1 = *(const bf16x8*)&As[wm*32 + 16 + lr][kofs];
    bf16x8 B0 = *(const bf16x8*)&Bs[wn*32 + lr][kofs];
    bf16x8 B1 = *(const bf16x8*)&Bs[wn*32 + 16 + lr][kofs];
    a00 = __builtin_amdgcn_mfma_f32_16x16x32_bf16(A0, B0, a00, 0, 0, 0);
    a01 = __builtin_amdgcn_mfma_f32_16x16x32_bf16(A0, B1, a01, 0, 0, 0);
    a10 = __builtin_amdgcn_mfma_f32_16x16x32_bf16(A1, B0, a10, 0, 0, 0);
    a11 = __builtin_amdgcn_mfma_f32_16x16x32_bf16(A1, B1, a11, 0, 0, 0);
}

// direct K-loop, K = 256 (node matrices)
__device__ __forceinline__ void gemm_direct256(const short* __restrict__ A, int row0,
    const short* __restrict__ Wt, int col0, int tid, int lane, int wm, int wn,
    short (*As)[40], short (*Bs)[40],
    f32x4& a00, f32x4& a01, f32x4& a10, f32x4& a11)
{
    for (int k0 = 0; k0 < DND; k0 += 32){
        {
            int r = tid>>2, ks = tid&3, k = k0 + ks*8;
            bf16x8 v = {0,0,0,0,0,0,0,0};
            int gr = row0 + r;
            if (gr < NN) v = *(const bf16x8*)&A[(size_t)gr*DND + k];
            *(bf16x8*)&As[r][ks*8] = v;
        }
        stageB(Bs, Wt, col0, DND, DND, DND, k0, tid);
        __syncthreads();
        mfma_step(As, Bs, wm, wn, lane, a00, a01, a10, a11);
        __syncthreads();
    }
}

// ---------------- generic C = act(A@Wt^T + b) ----------------
template<int ACT, bool F32OUT>   // ACT: 0 none, 1 relu
__global__ __launch_bounds__(256) void k_mm(const short* __restrict__ A,
                      const short* __restrict__ Wt, const float* __restrict__ bias,
                      void* __restrict__ Cv,
                      int M, int K, int N, int ldA, int ldW, int ldC)
{
    __shared__ short As[64][40];
    __shared__ short Bs[64][40];
    const int tid = threadIdx.x, lane = tid & 63, wave = tid >> 6;
    const int wm = wave >> 1, wn = wave & 1;
    const int row0 = blockIdx.y << 6, col0 = blockIdx.x << 6;
    f32x4 a00={0,0,0,0}, a01={0,0,0,0}, a10={0,0,0,0}, a11={0,0,0,0};
    for (int k0 = 0; k0 < K; k0 += 32){
        {
            int r = tid>>2, ks = tid&3, k = k0 + ks*8;
            bf16x8 v = {0,0,0,0,0,0,0,0};
            int gr = row0 + r;
            if (gr < M && k < K) v = *(const bf16x8*)&A[(size_t)gr*ldA + k];
            *(bf16x8*)&As[r][ks*8] = v;
        }
        stageB(Bs, Wt, col0, N, K, ldW, k0, tid);
        __syncthreads();
        mfma_step(As, Bs, wm, wn, lane, a00, a01, a10, a11);
        __syncthreads();
    }
    const int lr = lane & 15, lq = lane >> 4;
    f32x4 accs[2][2] = {{a00,a01},{a10,a11}};
    #pragma unroll
    for (int i = 0; i < 2; ++i)
      #pragma unroll
      for (int j = 0; j < 2; ++j){
        int col = col0 + wn*32 + j*16 + lr;
        if (col >= ldC) continue;
        bool valid = col < N;
        float bs = (valid && bias) ? bias[col] : 0.f;
        #pragma unroll
        for (int q = 0; q < 4; ++q){
            int row = row0 + wm*32 + i*16 + lq*4 + q;
            if (row >= M) continue;
            float v = valid ? (accs[i][j][q] + bs) : 0.f;
            if (ACT == 1) v = fmaxf(v, 0.f);
            if (F32OUT) ((float*)Cv)[(size_t)row*ldC + col] = v;
            else        ((short*)Cv)[(size_t)row*ldC + col] = f2b(v);
        }
      }
}

// ------- msg: sigm(V[s2[e]] + ec@W1e + b1) scatter-> agg  (K=96 GEMM) -------
__global__ __launch_bounds__(256) void k_msgf(const short* __restrict__ ec16,
                       const float* __restrict__ V,
                       const int* __restrict__ s2, const int* __restrict__ dst,
                       const short* __restrict__ WeT, const float* __restrict__ b1,
                       float* __restrict__ agg)
{
    __shared__ short As[64][40];
    __shared__ short Bs[64][40];
    __shared__ int ss[64], dd[64];
    const int tid = threadIdx.x, lane = tid & 63, wave = tid >> 6;
    const int wm = wave >> 1, wn = wave & 1;
    const int e0 = blockIdx.y << 6, col0 = blockIdx.x << 6;
    if (tid < 64){ ss[tid] = s2[e0+tid]; dd[tid] = dst[e0+tid]; }
    f32x4 a00={0,0,0,0}, a01={0,0,0,0}, a10={0,0,0,0}, a11={0,0,0,0};
    for (int k0 = 0; k0 < DEC; k0 += 32){
        {
            int r = tid>>2, ks = tid&3, k = k0 + ks*8;
            *(bf16x8*)&As[r][ks*8] = *(const bf16x8*)&ec16[(size_t)(e0+r)*DEC + k];
        }
        stageB(Bs, WeT, col0, DAC, DEC, DEC, k0, tid);
        __syncthreads();
        mfma_step(As, Bs, wm, wn, lane, a00, a01, a10, a11);
        __syncthreads();
    }
    const int lr = lane & 15, lq = lane >> 4;
    f32x4 accs[2][2] = {{a00,a01},{a10,a11}};
    #pragma unroll
    for (int i = 0; i < 2; ++i)
      #pragma unroll
      for (int j = 0; j < 2; ++j){
        int col = col0 + wn*32 + j*16 + lr;
        if (col >= DAC) continue;
        float bs = b1[col];
        #pragma unroll
        for (int q = 0; q < 4; ++q){
            int rl = wm*32 + i*16 + lq*4 + q;
            float v = sigm(accs[i][j][q] + V[(size_t)ss[rl]*DAC + col] + bs);
            atomicAdd(&agg[(size_t)dd[rl]*DAC + col], v);
        }
      }
}

// ------- h2 = sigm(U1[src]+ec@WE1e+be1) + sigm(U2[dst]+ec@W1e+b1) -> bf16 -------
__global__ __launch_bounds__(256) void k_h2f(const short* __restrict__ ec16,
                       const float* __restrict__ U1, const float* __restrict__ U2,
                       const int* __restrict__ src, const int* __restrict__ dst,
                       const short* __restrict__ WsT, const float* __restrict__ bsv,
                       const short* __restrict__ WtT, const float* __restrict__ btv,
                       short* __restrict__ h2)
{
    __shared__ short As[64][40];
    __shared__ short B1s[64][40];
    __shared__ short B2s[64][40];
    __shared__ int ss[64], dd[64];
    const int tid = threadIdx.x, lane = tid & 63, wave = tid >> 6;
    const int wm = wave >> 1, wn = wave & 1;
    const int e0 = blockIdx.y << 6, col0 = blockIdx.x << 6;
    if (tid < 64){ ss[tid] = src[e0+tid]; dd[tid] = dst[e0+tid]; }
    f32x4 s00={0,0,0,0}, s01={0,0,0,0}, s10={0,0,0,0}, s11={0,0,0,0};
    f32x4 t00={0,0,0,0}, t01={0,0,0,0}, t10={0,0,0,0}, t11={0,0,0,0};
    for (int k0 = 0; k0 < DEC; k0 += 32){
        {
            int r = tid>>2, ks = tid&3, k = k0 + ks*8;
            *(bf16x8*)&As[r][ks*8] = *(const bf16x8*)&ec16[(size_t)(e0+r)*DEC + k];
        }
        stageB(B1s, WsT, col0, DAC, DEC, DEC, k0, tid);
        stageB(B2s, WtT, col0, DAC, DEC, DEC, k0, tid);
        __syncthreads();
        mfma_step(As, B1s, wm, wn, lane, s00, s01, s10, s11);
        mfma_step(As, B2s, wm, wn, lane, t00, t01, t10, t11);
        __syncthreads();
    }
    const int lr = lane & 15, lq = lane >> 4;
    f32x4 sa[2][2] = {{s00,s01},{s10,s11}};
    f32x4 ta[2][2] = {{t00,t01},{t10,t11}};
    #pragma unroll
    for (int i = 0; i < 2; ++i)
      #pragma unroll
      for (int j = 0; j < 2; ++j){
        int col = col0 + wn*32 + j*16 + lr;
        if (col >= DAC) continue;
        float cbs = bsv[col], cbt = btv[col];
        #pragma unroll
        for (int q = 0; q < 4; ++q){
            int rl = wm*32 + i*16 + lq*4 + q;
            float v = sigm(sa[i][j][q] + U1[(size_t)ss[rl]*DAC + col] + cbs)
                    + sigm(ta[i][j][q] + U2[(size_t)dd[rl]*DAC + col] + cbt);
            h2[(size_t)(e0+rl)*DAC + col] = f2b(v);
        }
      }
}

// ---------------- node update ----------------
__global__ __launch_bounds__(256) void k_nodeup(const short* __restrict__ nf16,
                       const short* __restrict__ m16,
                       const short* __restrict__ Wlst, const short* __restrict__ Wlnt,
                       const float* __restrict__ bls, const float* __restrict__ bln,
                       const float* __restrict__ nf, float* __restrict__ nfu,
                       short* __restrict__ nfu16)
{
    __shared__ short As[64][40];
    __shared__ short Bs[64][40];
    const int tid = threadIdx.x, lane = tid & 63, wave = tid >> 6;
    const int wm = wave >> 1, wn = wave & 1;
    const int row0 = blockIdx.y << 6, col0 = blockIdx.x << 6;
    f32x4 s00={0,0,0,0}, s01={0,0,0,0}, s10={0,0,0,0}, s11={0,0,0,0};
    f32x4 t00={0,0,0,0}, t01={0,0,0,0}, t10={0,0,0,0}, t11={0,0,0,0};
    gemm_direct256(nf16, row0, Wlst, col0, tid, lane, wm, wn, As, Bs, s00,s01,s10,s11);
    gemm_direct256(m16,  row0, Wlnt, col0, tid, lane, wm, wn, As, Bs, t00,t01,t10,t11);
    const int lr = lane & 15, lq = lane >> 4;
    f32x4 sa[2][2] = {{s00,s01},{s10,s11}};
    f32x4 ta[2][2] = {{t00,t01},{t10,t11}};
    #pragma unroll
    for (int i = 0; i < 2; ++i)
      #pragma unroll
      for (int j = 0; j < 2; ++j){
        int col = col0 + wn*32 + j*16 + lr;
        float bb = bls[col] + bln[col];
        #pragma unroll
        for (int q = 0; q < 4; ++q){
            int row = row0 + wm*32 + i*16 + lq*4 + q;
            if (row >= NN) continue;
            float v = sigm(sa[i][j][q] + ta[i][j][q] + bb) + nf[(size_t)row*DND + col];
            nfu[(size_t)row*DND + col] = v;
            nfu16[(size_t)row*DND + col] = f2b(v);
        }
      }
}

extern "C" void kernel_launch(void* const* d_in, const int* in_sizes, int n_in,
                              void* d_out, int out_size, void* d_ws, size_t ws_size,
                              hipStream_t stream)
{
    const float* NF  = (const float*)d_in[0];
    const float* ERD = (const float*)d_in[1];
    const float* EAD = (const float*)d_in[2];
    const int*   EIX = (const int*)d_in[3];
    const int* src = EIX; const int* dst = EIX + NE;
    const float* W1   = (const float*)d_in[4];  const float* B1   = (const float*)d_in[5];
    const float* W20  = (const float*)d_in[6];  const float* B20  = (const float*)d_in[7];
    const float* W21  = (const float*)d_in[8];  const float* B21  = (const float*)d_in[9];
    const float* W22  = (const float*)d_in[10]; const float* B22  = (const float*)d_in[11];
    const float* W23  = (const float*)d_in[12]; const float* B23  = (const float*)d_in[13];
    const float* WLS  = (const float*)d_in[14]; const float* BLS  = (const float*)d_in[15];
    const float* WLN  = (const float*)d_in[16]; const float* BLN  = (const float*)d_in[17];
    const float* WE1  = (const float*)d_in[18]; const float* BE1  = (const float*)d_in[19];
    const float* WE20 = (const float*)d_in[20]; const float* BE20 = (const float*)d_in[21];
    const float* WE21 = (const float*)d_in[22]; const float* BE21 = (const float*)d_in[23];
    const float* WE22 = (const float*)d_in[24]; const float* BE22 = (const float*)d_in[25];
    const float* WE23 = (const float*)d_in[26]; const float* BE23 = (const float*)d_in[27];

    float* nfu = (float*)d_out;
    float* efu = nfu + (size_t)NN*DND;

    char* p = (char*)d_ws;
    auto alloc = [&](size_t bytes)->char*{ char* q = p; p += (bytes + 255) & ~(size_t)255; return q; };
    // persistent
    int*   s2    = (int*)  alloc((size_t)NE*4);
    short* nf16  = (short*)alloc((size_t)NN*DND*2);
    short* ec16  = (short*)alloc((size_t)NE*DEC*2);
    short* nfu16 = (short*)alloc((size_t)NN*DND*2);
    short* wpool = (short*)alloc((size_t)600000*2);
    // slabA: node-phase scratch, later re-used for U1/U2
    char*  slabA = alloc((size_t)36*1024*1024);
    float* agg   = (float*)slabA;                               // [NN*352] f32
    float* V     = (float*)(slabA + (size_t)NN*DAC*4);          // [NN*352] f32 (dead before agg16 written)
    short* agg16 = (short*)(slabA + (size_t)NN*DAC*4);          // aliases V (V dead by then)
    short* h0    = (short*)((char*)agg16 + (size_t)NN*DAC*2);   // [NN*208]
    short* h1    = (short*)((char*)h0 + (size_t)NN*208*2);      // [NN*64]
    short* h2n   = (short*)((char*)h1 + (size_t)NN*64*2);       // [NN*128]
    short* m16   = (short*)((char*)h2n + (size_t)NN*128*2);     // [NN*256]
    float* U1    = (float*)slabA;                               // after node phase dead
    float* U2    = (float*)(slabA + (size_t)NN*DAC*4);
    // slabB: edge-phase
    short* h2e   = (short*)alloc((size_t)NE*DAC*2);             // 112.6 MB
    short* e0b   = (short*)alloc((size_t)NE*192*2);             // 61.4 MB
    short* e1b   = (short*)h2e;                                 // aliases h2e (dead after e0b GEMM)
    short* e2b   = (short*)((char*)h2e + (size_t)8*1024*1024);

    // weight pool offsets (elements)
    long long off = 0; WtJobs jobs; int nj = 0;
    auto addjob = [&](const float* W, int K, int N, int ld)->long long{
        long long o = off;
        jobs.j[nj] = { W, o, K, N, ld, N*ld };
        off += (long long)N*ld; ++nj; return o;
    };
    short* W1n  = wpool + addjob(W1,            256, 352, 256);
    short* W1e  = wpool + addjob(W1 + 256*352,   96, 352,  96);
    short* WE1n = wpool + addjob(WE1,           256, 352, 256);
    short* WE1e = wpool + addjob(WE1 + 256*352,  96, 352,  96);
    short* W20t = wpool + addjob(W20, 352, 208, 352);
    short* W21t = wpool + addjob(W21, 208,  64, 208);
    short* W22t = wpool + addjob(W22,  64, 128,  64);
    short* W23t = wpool + addjob(W23, 128, 256, 128);
    short* WLSt = wpool + addjob(WLS, 256, 256, 256);
    short* WLNt = wpool + addjob(WLN, 256, 256, 256);
    short* WE20t= wpool + addjob(WE20, 352, 188, 352);
    short* WE21t= wpool + addjob(WE21, 188,  24, 192);
    short* WE22t= wpool + addjob(WE22,  24,  48,  24);
    short* WE23t= wpool + addjob(WE23,  48,  96,  48);
    jobs.grand = (int)off;

    // ---- prep ----
    k_s2  <<<dim3((NE+255)/256), 256, 0, stream>>>(src, s2);
    k_prep<<<dim3(2048), 256, 0, stream>>>(NF, ERD, EAD, nf16, ec16);
    k_wtall<<<dim3((jobs.grand+255)/256), 256, 0, stream>>>(jobs, wpool);

    // ---- node phase ----
    k_mm<0,true><<<dim3(6,157), 256, 0, stream>>>(nf16, W1n, nullptr, V, NN, 256, 352, 256, 256, 352);
    hipMemsetAsync(agg, 0, sizeof(float)*(size_t)NN*DAC, stream);
    k_msgf<<<dim3(6, NE/64), 256, 0, stream>>>(ec16, V, s2, dst, W1e, B1, agg);
    k_cvt<<<dim3(2048), 256, 0, stream>>>(agg, agg16, NN*DAC);
    k_mm<1,false><<<dim3(4,157), 256, 0, stream>>>(agg16, W20t, B20, h0,  NN, 352, 208, 352, 352, 208);
    k_mm<1,false><<<dim3(1,157), 256, 0, stream>>>(h0,   W21t, B21, h1,  NN, 208, 64,  208, 208, 64);
    k_mm<1,false><<<dim3(2,157), 256, 0, stream>>>(h1,   W22t, B22, h2n, NN, 64,  128, 64,  64,  128);
    k_mm<0,false><<<dim3(4,157), 256, 0, stream>>>(h2n,  W23t, B23, m16, NN, 128, 256, 128, 128, 256);
    k_nodeup<<<dim3(4,157), 256, 0, stream>>>(nf16, m16, WLSt, WLNt, BLS, BLN, NF, nfu, nfu16);

    // ---- edge phase ----
    k_mm<0,true><<<dim3(6,157), 256, 0, stream>>>(nfu16, WE1n, nullptr, U1, NN, 256, 352, 256, 256, 352);
    k_mm<0,true><<<dim3(6,157), 256, 0, stream>>>(nfu16, W1n,  nullptr, U2, NN, 256, 352, 256, 256, 352);
    k_h2f<<<dim3(6, NE/64), 256, 0, stream>>>(ec16, U1, U2, src, dst, WE1e, BE1, W1e, B1, h2e);
    k_mm<1,false><<<dim3(3, NE/64), 256, 0, stream>>>(h2e, WE20t, BE20, e0b, NE, 352, 188, 352, 352, 192);
    k_mm<1,false><<<dim3(1, NE/64), 256, 0, stream>>>(e0b, WE21t, BE21, e1b, NE, 188, 24,  192, 192, 24);
    k_mm<1,false><<<dim3(1, NE/64), 256, 0, stream>>>(e1b, WE22t, BE22, e2b, NE, 24,  48,  24,  24,  48);
    k_mm<0,true ><<<dim3(2, NE/64), 256, 0, stream>>>(e2b, WE23t, BE23, efu, NE, 48,  96,  48,  48,  96);
}

// Round 11
// 725.561 us; speedup vs baseline: 9.0084x; 1.0325x over previous
//
#include <hip/hip_runtime.h>
#include <math.h>

#define NN 10000
#define NE 160000
#define DND 256
#define DER 64
#define DEA 32
#define DEC 96
#define DAC 352

typedef __attribute__((ext_vector_type(4))) float f32x4;
typedef __attribute__((ext_vector_type(8))) short bf16x8;

__device__ __forceinline__ float sigm(float x){ return 1.0f/(1.0f+expf(-x)); }
__device__ __forceinline__ short f2b(float x){
    union { float f; unsigned u; } v; v.f = x;
    unsigned r = v.u + 0x7FFFu + ((v.u >> 16) & 1u);
    return (short)(r >> 16);
}
__device__ __forceinline__ float b2f(short s){
    union { float f; unsigned u; } v; v.u = ((unsigned)(unsigned short)s) << 16; return v.f;
}

// ---------------- s2[i] = src[src[i]] (reference quirk) ----------------
__global__ void k_s2(const int* __restrict__ src, int* __restrict__ s2){
    int i = blockIdx.x*256 + threadIdx.x;
    if (i < NE) s2[i] = src[src[i]];
}

// ---------------- dst histogram / scan / scatter (counting sort by dst) ----------------
__global__ void k_hist(const int* __restrict__ dst, int* __restrict__ cnt){
    int i = blockIdx.x*256 + threadIdx.x;
    if (i < NE) atomicAdd(&cnt[dst[i]], 1);
}
__global__ void k_scan(const int* __restrict__ cnt, int* __restrict__ cursor){
    __shared__ int sums[256];
    const int tid = threadIdx.x;
    const int CH = (NN + 255) / 256;            // 40
    int base = tid * CH, s = 0;
    for (int i = 0; i < CH; ++i){ int idx = base + i; if (idx < NN) s += cnt[idx]; }
    sums[tid] = s; __syncthreads();
    for (int off = 1; off < 256; off <<= 1){
        int t = (tid >= off) ? sums[tid - off] : 0;
        __syncthreads();
        sums[tid] += t;
        __syncthreads();
    }
    int run = sums[tid] - s;                    // exclusive base for this chunk
    for (int i = 0; i < CH; ++i){
        int idx = base + i;
        if (idx < NN){ cursor[idx] = run; run += cnt[idx]; }
    }
}
__global__ void k_scat(const int* __restrict__ dst, int* __restrict__ cursor,
                       int* __restrict__ perm){
    int i = blockIdx.x*256 + threadIdx.x;
    if (i < NE){ int p = atomicAdd(&cursor[dst[i]], 1); perm[p] = i; }
}

// ---------------- fused prep: nf16 + ec16 ----------------
__global__ void k_prep(const float* __restrict__ nf, const float* __restrict__ er,
                       const float* __restrict__ ea,
                       short* __restrict__ nf16, short* __restrict__ ec16){
    const int n1 = NN*DND, n2 = NE*DEC;
    int i = blockIdx.x*256 + threadIdx.x;
    int stride = gridDim.x*256;
    for (; i < n1 + n2; i += stride){
        if (i < n1) nf16[i] = f2b(nf[i]);
        else {
            int t = i - n1;
            int e = t / DEC, c = t - e*DEC;
            float v = (c < DER) ? er[(size_t)e*DER + c] : ea[(size_t)e*DEA + (c-DER)];
            ec16[t] = f2b(v);
        }
    }
}

// ---------------- f32 -> bf16 ----------------
__global__ void k_cvt(const float* __restrict__ in, short* __restrict__ out, int n){
    int i = blockIdx.x*256 + threadIdx.x;
    int stride = gridDim.x*256;
    for (; i < n; i += stride) out[i] = f2b(in[i]);
}

// ---------------- all weight transposes in one launch ----------------
struct WtJob { const float* W; long long dstOff; int K, N, ld, total; };
struct WtJobs { WtJob j[14]; int grand; };
__global__ void k_wtall(WtJobs jobs, short* __restrict__ pool){
    int i = blockIdx.x*256 + threadIdx.x;
    int stride = gridDim.x*256;
    for (; i < jobs.grand; i += stride){
        int t = i, jj = 0;
        while (t >= jobs.j[jj].total){ t -= jobs.j[jj].total; ++jj; }
        const WtJob J = jobs.j[jj];
        int n = t / J.ld, k = t - n*J.ld;
        pool[J.dstOff + t] = (k < J.K) ? f2b(J.W[(size_t)k*J.N + n]) : (short)0;
    }
}

// ---------------- MFMA helpers ----------------
__device__ __forceinline__ void stageB(short (*Bs)[40], const short* __restrict__ Wt,
                                       int col0, int N, int K, int ldW, int k0, int tid){
    int c = tid>>2, ks = tid&3, k = k0 + ks*8;
    bf16x8 v = {0,0,0,0,0,0,0,0};
    int gc = col0 + c;
    if (gc < N && k < K) v = *(const bf16x8*)&Wt[(size_t)gc*ldW + k];
    *(bf16x8*)&Bs[c][ks*8] = v;
}

__device__ __forceinline__ void mfma_step(const short (*As)[40], const short (*Bs)[40],
                                          int wm, int wn, int lane,
                                          f32x4& a00, f32x4& a01, f32x4& a10, f32x4& a11){
    const int kofs = (lane>>4)*8, lr = lane & 15;
    bf16x8 A0 = *(const bf16x8*)&As[wm*32 + lr][kofs];
    bf16x8 A1 = *(const bf16x8*)&As[wm*32 + 16 + lr][kofs];
    bf16x8 B0 = *(const bf16x8*)&Bs[wn*32 + lr][kofs];
    bf16x8 B1 = *(const bf16x8*)&Bs[wn*32 + 16 + lr][kofs];
    a00 = __builtin_amdgcn_mfma_f32_16x16x32_bf16(A0, B0, a00, 0, 0, 0);
    a01 = __builtin_amdgcn_mfma_f32_16x16x32_bf16(A0, B1, a01, 0, 0, 0);
    a10 = __builtin_amdgcn_mfma_f32_16x16x32_bf16(A1, B0, a10, 0, 0, 0);
    a11 = __builtin_amdgcn_mfma_f32_16x16x32_bf16(A1, B1, a11, 0, 0, 0);
}

// direct K-loop, K = 256 (node matrices)
__device__ __forceinline__ void gemm_direct256(const short* __restrict__ A, int row0,
    const short* __restrict__ Wt, int col0, int tid, int lane, int wm, int wn,
    short (*As)[40], short (*Bs)[40],
    f32x4& a00, f32x4& a01, f32x4& a10, f32x4& a11)
{
    for (int k0 = 0; k0 < DND; k0 += 32){
        {
            int r = tid>>2, ks = tid&3, k = k0 + ks*8;
            bf16x8 v = {0,0,0,0,0,0,0,0};
            int gr = row0 + r;
            if (gr < NN) v = *(const bf16x8*)&A[(size_t)gr*DND + k];
            *(bf16x8*)&As[r][ks*8] = v;
        }
        stageB(Bs, Wt, col0, DND, DND, DND, k0, tid);
        __syncthreads();
        mfma_step(As, Bs, wm, wn, lane, a00, a01, a10, a11);
        __syncthreads();
    }
}

// ---------------- generic C = act(A@Wt^T + b) ----------------
template<int ACT, bool F32OUT>   // ACT: 0 none, 1 relu
__global__ __launch_bounds__(256) void k_mm(const short* __restrict__ A,
                      const short* __restrict__ Wt, const float* __restrict__ bias,
                      void* __restrict__ Cv,
                      int M, int K, int N, int ldA, int ldW, int ldC)
{
    __shared__ short As[64][40];
    __shared__ short Bs[64][40];
    const int tid = threadIdx.x, lane = tid & 63, wave = tid >> 6;
    const int wm = wave >> 1, wn = wave & 1;
    const int row0 = blockIdx.y << 6, col0 = blockIdx.x << 6;
    f32x4 a00={0,0,0,0}, a01={0,0,0,0}, a10={0,0,0,0}, a11={0,0,0,0};
    for (int k0 = 0; k0 < K; k0 += 32){
        {
            int r = tid>>2, ks = tid&3, k = k0 + ks*8;
            bf16x8 v = {0,0,0,0,0,0,0,0};
            int gr = row0 + r;
            if (gr < M && k < K) v = *(const bf16x8*)&A[(size_t)gr*ldA + k];
            *(bf16x8*)&As[r][ks*8] = v;
        }
        stageB(Bs, Wt, col0, N, K, ldW, k0, tid);
        __syncthreads();
        mfma_step(As, Bs, wm, wn, lane, a00, a01, a10, a11);
        __syncthreads();
    }
    const int lr = lane & 15, lq = lane >> 4;
    f32x4 accs[2][2] = {{a00,a01},{a10,a11}};
    #pragma unroll
    for (int i = 0; i < 2; ++i)
      #pragma unroll
      for (int j = 0; j < 2; ++j){
        int col = col0 + wn*32 + j*16 + lr;
        if (col >= ldC) continue;
        bool valid = col < N;
        float bs = (valid && bias) ? bias[col] : 0.f;
        #pragma unroll
        for (int q = 0; q < 4; ++q){
            int row = row0 + wm*32 + i*16 + lq*4 + q;
            if (row >= M) continue;
            float v = valid ? (accs[i][j][q] + bs) : 0.f;
            if (ACT == 1) v = fmaxf(v, 0.f);
            if (F32OUT) ((float*)Cv)[(size_t)row*ldC + col] = v;
            else        ((short*)Cv)[(size_t)row*ldC + col] = f2b(v);
        }
      }
}

// ------- msg (dst-sorted): sigm(V16[s2[perm]] + ec[perm]@W1e + b1), segmented reduce -> agg -------
__global__ __launch_bounds__(256) void k_msga(const short* __restrict__ ec16,
                       const short* __restrict__ V16,
                       const int* __restrict__ perm,
                       const int* __restrict__ s2, const int* __restrict__ dst,
                       const short* __restrict__ WeT, const float* __restrict__ b1,
                       float* __restrict__ agg)
{
    __shared__ short As[64][40];
    __shared__ short Bs[64][40];
    __shared__ float vals[64][65];
    __shared__ int pe[64], ss[64], dd[64];
    const int tid = threadIdx.x, lane = tid & 63, wave = tid >> 6;
    const int wm = wave >> 1, wn = wave & 1;
    const int e0 = blockIdx.y << 6, col0 = blockIdx.x << 6;
    if (tid < 64){
        int e = perm[e0 + tid];
        pe[tid] = e; ss[tid] = s2[e]; dd[tid] = dst[e];
    }
    __syncthreads();
    f32x4 a00={0,0,0,0}, a01={0,0,0,0}, a10={0,0,0,0}, a11={0,0,0,0};
    for (int k0 = 0; k0 < DEC; k0 += 32){
        {
            int r = tid>>2, ks = tid&3, k = k0 + ks*8;
            *(bf16x8*)&As[r][ks*8] = *(const bf16x8*)&ec16[(size_t)pe[r]*DEC + k];
        }
        stageB(Bs, WeT, col0, DAC, DEC, DEC, k0, tid);
        __syncthreads();
        mfma_step(As, Bs, wm, wn, lane, a00, a01, a10, a11);
        __syncthreads();
    }
    const int lr = lane & 15, lq = lane >> 4;
    f32x4 accs[2][2] = {{a00,a01},{a10,a11}};
    #pragma unroll
    for (int i = 0; i < 2; ++i)
      #pragma unroll
      for (int j = 0; j < 2; ++j){
        int cl = wn*32 + j*16 + lr;
        int gc = col0 + cl;
        float bs = (gc < DAC) ? b1[gc] : 0.f;
        #pragma unroll
        for (int q = 0; q < 4; ++q){
            int rl = wm*32 + i*16 + lq*4 + q;
            float v = 0.f;
            if (gc < DAC)
                v = sigm(accs[i][j][q] + b2f(V16[(size_t)ss[rl]*DAC + gc]) + bs);
            vals[rl][cl] = v;
        }
      }
    __syncthreads();
    // segmented (run-length) reduction over dst-sorted rows: ~2 atomics / 16 rows
    int c = tid & 63, gc2 = col0 + c;
    if (gc2 < DAC){
        int r0 = (tid >> 6) * 16;
        float run = vals[r0][c]; int cur = dd[r0];
        #pragma unroll
        for (int r = r0 + 1; r < r0 + 16; ++r){
            int n = dd[r]; float v = vals[r][c];
            if (n == cur) run += v;
            else { atomicAdd(&agg[(size_t)cur*DAC + gc2], run); cur = n; run = v; }
        }
        atomicAdd(&agg[(size_t)cur*DAC + gc2], run);
    }
}

// ------- h2 = sigm(U1[src]+ec@WE1e+be1) + sigm(U2[dst]+ec@W1e+b1) -> bf16 -------
__global__ __launch_bounds__(256) void k_h2f(const short* __restrict__ ec16,
                       const short* __restrict__ U1, const short* __restrict__ U2,
                       const int* __restrict__ src, const int* __restrict__ dst,
                       const short* __restrict__ WsT, const float* __restrict__ bsv,
                       const short* __restrict__ WtT, const float* __restrict__ btv,
                       short* __restrict__ h2)
{
    __shared__ short As[64][40];
    __shared__ short B1s[64][40];
    __shared__ short B2s[64][40];
    __shared__ int ss[64], dd[64];
    const int tid = threadIdx.x, lane = tid & 63, wave = tid >> 6;
    const int wm = wave >> 1, wn = wave & 1;
    const int e0 = blockIdx.y << 6, col0 = blockIdx.x << 6;
    if (tid < 64){ ss[tid] = src[e0+tid]; dd[tid] = dst[e0+tid]; }
    f32x4 s00={0,0,0,0}, s01={0,0,0,0}, s10={0,0,0,0}, s11={0,0,0,0};
    f32x4 t00={0,0,0,0}, t01={0,0,0,0}, t10={0,0,0,0}, t11={0,0,0,0};
    for (int k0 = 0; k0 < DEC; k0 += 32){
        {
            int r = tid>>2, ks = tid&3, k = k0 + ks*8;
            *(bf16x8*)&As[r][ks*8] = *(const bf16x8*)&ec16[(size_t)(e0+r)*DEC + k];
        }
        stageB(B1s, WsT, col0, DAC, DEC, DEC, k0, tid);
        stageB(B2s, WtT, col0, DAC, DEC, DEC, k0, tid);
        __syncthreads();
        mfma_step(As, B1s, wm, wn, lane, s00, s01, s10, s11);
        mfma_step(As, B2s, wm, wn, lane, t00, t01, t10, t11);
        __syncthreads();
    }
    const int lr = lane & 15, lq = lane >> 4;
    f32x4 sa[2][2] = {{s00,s01},{s10,s11}};
    f32x4 ta[2][2] = {{t00,t01},{t10,t11}};
    #pragma unroll
    for (int i = 0; i < 2; ++i)
      #pragma unroll
      for (int j = 0; j < 2; ++j){
        int col = col0 + wn*32 + j*16 + lr;
        if (col >= DAC) continue;
        float cbs = bsv[col], cbt = btv[col];
        #pragma unroll
        for (int q = 0; q < 4; ++q){
            int rl = wm*32 + i*16 + lq*4 + q;
            float v = sigm(sa[i][j][q] + b2f(U1[(size_t)ss[rl]*DAC + col]) + cbs)
                    + sigm(ta[i][j][q] + b2f(U2[(size_t)dd[rl]*DAC + col]) + cbt);
            h2[(size_t)(e0+rl)*DAC + col] = f2b(v);
        }
      }
}

// ---------------- node update ----------------
__global__ __launch_bounds__(256) void k_nodeup(const short* __restrict__ nf16,
                       const short* __restrict__ m16,
                       const short* __restrict__ Wlst, const short* __restrict__ Wlnt,
                       const float* __restrict__ bls, const float* __restrict__ bln,
                       const float* __restrict__ nf, float* __restrict__ nfu,
                       short* __restrict__ nfu16)
{
    __shared__ short As[64][40];
    __shared__ short Bs[64][40];
    const int tid = threadIdx.x, lane = tid & 63, wave = tid >> 6;
    const int wm = wave >> 1, wn = wave & 1;
    const int row0 = blockIdx.y << 6, col0 = blockIdx.x << 6;
    f32x4 s00={0,0,0,0}, s01={0,0,0,0}, s10={0,0,0,0}, s11={0,0,0,0};
    f32x4 t00={0,0,0,0}, t01={0,0,0,0}, t10={0,0,0,0}, t11={0,0,0,0};
    gemm_direct256(nf16, row0, Wlst, col0, tid, lane, wm, wn, As, Bs, s00,s01,s10,s11);
    gemm_direct256(m16,  row0, Wlnt, col0, tid, lane, wm, wn, As, Bs, t00,t01,t10,t11);
    const int lr = lane & 15, lq = lane >> 4;
    f32x4 sa[2][2] = {{s00,s01},{s10,s11}};
    f32x4 ta[2][2] = {{t00,t01},{t10,t11}};
    #pragma unroll
    for (int i = 0; i < 2; ++i)
      #pragma unroll
      for (int j = 0; j < 2; ++j){
        int col = col0 + wn*32 + j*16 + lr;
        float bb = bls[col] + bln[col];
        #pragma unroll
        for (int q = 0; q < 4; ++q){
            int row = row0 + wm*32 + i*16 + lq*4 + q;
            if (row >= NN) continue;
            float v = sigm(sa[i][j][q] + ta[i][j][q] + bb) + nf[(size_t)row*DND + col];
            nfu[(size_t)row*DND + col] = v;
            nfu16[(size_t)row*DND + col] = f2b(v);
        }
      }
}

extern "C" void kernel_launch(void* const* d_in, const int* in_sizes, int n_in,
                              void* d_out, int out_size, void* d_ws, size_t ws_size,
                              hipStream_t stream)
{
    const float* NF  = (const float*)d_in[0];
    const float* ERD = (const float*)d_in[1];
    const float* EAD = (const float*)d_in[2];
    const int*   EIX = (const int*)d_in[3];
    const int* src = EIX; const int* dst = EIX + NE;
    const float* W1   = (const float*)d_in[4];  const float* B1   = (const float*)d_in[5];
    const float* W20  = (const float*)d_in[6];  const float* B20  = (const float*)d_in[7];
    const float* W21  = (const float*)d_in[8];  const float* B21  = (const float*)d_in[9];
    const float* W22  = (const float*)d_in[10]; const float* B22  = (const float*)d_in[11];
    const float* W23  = (const float*)d_in[12]; const float* B23  = (const float*)d_in[13];
    const float* WLS  = (const float*)d_in[14]; const float* BLS  = (const float*)d_in[15];
    const float* WLN  = (const float*)d_in[16]; const float* BLN  = (const float*)d_in[17];
    const float* WE1  = (const float*)d_in[18]; const float* BE1  = (const float*)d_in[19];
    const float* WE20 = (const float*)d_in[20]; const float* BE20 = (const float*)d_in[21];
    const float* WE21 = (const float*)d_in[22]; const float* BE21 = (const float*)d_in[23];
    const float* WE22 = (const float*)d_in[24]; const float* BE22 = (const float*)d_in[25];
    const float* WE23 = (const float*)d_in[26]; const float* BE23 = (const float*)d_in[27];

    float* nfu = (float*)d_out;
    float* efu = nfu + (size_t)NN*DND;

    char* p = (char*)d_ws;
    auto alloc = [&](size_t bytes)->char*{ char* q = p; p += (bytes + 255) & ~(size_t)255; return q; };
    // persistent
    int*   s2    = (int*)  alloc((size_t)NE*4);
    int*   perm  = (int*)  alloc((size_t)NE*4);
    int*   cnt   = (int*)  alloc((size_t)NN*4);
    int*   cursor= (int*)  alloc((size_t)NN*4);
    short* nf16  = (short*)alloc((size_t)NN*DND*2);
    short* ec16  = (short*)alloc((size_t)NE*DEC*2);
    short* nfu16 = (short*)alloc((size_t)NN*DND*2);
    short* wpool = (short*)alloc((size_t)600000*2);
    // slabA: node-phase scratch, later reused for U1/U2 (bf16)
    char*  slabA = alloc((size_t)36*1024*1024);
    float* agg   = (float*)slabA;                               // [NN*352] f32 (14.08 MB)
    short* V16   = (short*)(slabA + (size_t)NN*DAC*4);          // [NN*352] bf16 (7.04 MB)
    short* agg16 = V16;                                         // aliases V16 (V16 dead after k_msga)
    short* h0    = (short*)((char*)V16 + (size_t)NN*DAC*2);     // [NN*208]
    short* h1    = (short*)((char*)h0 + (size_t)NN*208*2);      // [NN*64]
    short* h2n   = (short*)((char*)h1 + (size_t)NN*64*2);       // [NN*128]
    short* m16   = (short*)((char*)h2n + (size_t)NN*128*2);     // [NN*256]
    short* U1    = (short*)slabA;                               // agg dead in edge phase
    short* U2    = (short*)(slabA + (size_t)NN*DAC*2);
    // slabB: edge-phase
    short* h2e   = (short*)alloc((size_t)NE*DAC*2);             // 112.6 MB
    short* e0b   = (short*)alloc((size_t)NE*192*2);             // 61.4 MB
    short* e1b   = (short*)h2e;                                 // aliases h2e (dead after e0b GEMM)
    short* e2b   = (short*)((char*)h2e + (size_t)8*1024*1024);

    // weight pool offsets (elements)
    long long off = 0; WtJobs jobs; int nj = 0;
    auto addjob = [&](const float* W, int K, int N, int ld)->long long{
        long long o = off;
        jobs.j[nj] = { W, o, K, N, ld, N*ld };
        off += (long long)N*ld; ++nj; return o;
    };
    short* W1n  = wpool + addjob(W1,            256, 352, 256);
    short* W1e  = wpool + addjob(W1 + 256*352,   96, 352,  96);
    short* WE1n = wpool + addjob(WE1,           256, 352, 256);
    short* WE1e = wpool + addjob(WE1 + 256*352,  96, 352,  96);
    short* W20t = wpool + addjob(W20, 352, 208, 352);
    short* W21t = wpool + addjob(W21, 208,  64, 208);
    short* W22t = wpool + addjob(W22,  64, 128,  64);
    short* W23t = wpool + addjob(W23, 128, 256, 128);
    short* WLSt = wpool + addjob(WLS, 256, 256, 256);
    short* WLNt = wpool + addjob(WLN, 256, 256, 256);
    short* WE20t= wpool + addjob(WE20, 352, 188, 352);
    short* WE21t= wpool + addjob(WE21, 188,  24, 192);
    short* WE22t= wpool + addjob(WE22,  24,  48,  24);
    short* WE23t= wpool + addjob(WE23,  48,  96,  48);
    jobs.grand = (int)off;

    // ---- prep ----
    k_s2  <<<dim3((NE+255)/256), 256, 0, stream>>>(src, s2);
    hipMemsetAsync(cnt, 0, (size_t)NN*4, stream);
    k_hist<<<dim3((NE+255)/256), 256, 0, stream>>>(dst, cnt);
    k_scan<<<dim3(1), 256, 0, stream>>>(cnt, cursor);
    k_scat<<<dim3((NE+255)/256), 256, 0, stream>>>(dst, cursor, perm);
    k_prep<<<dim3(2048), 256, 0, stream>>>(NF, ERD, EAD, nf16, ec16);
    k_wtall<<<dim3((jobs.grand+255)/256), 256, 0, stream>>>(jobs, wpool);

    // ---- node phase ----
    k_mm<0,false><<<dim3(6,157), 256, 0, stream>>>(nf16, W1n, nullptr, V16, NN, 256, 352, 256, 256, 352);
    hipMemsetAsync(agg, 0, sizeof(float)*(size_t)NN*DAC, stream);
    k_msga<<<dim3(6, NE/64), 256, 0, stream>>>(ec16, V16, perm, s2, dst, W1e, B1, agg);
    k_cvt<<<dim3(2048), 256, 0, stream>>>(agg, agg16, NN*DAC);
    k_mm<1,false><<<dim3(4,157), 256, 0, stream>>>(agg16, W20t, B20, h0,  NN, 352, 208, 352, 352, 208);
    k_mm<1,false><<<dim3(1,157), 256, 0, stream>>>(h0,   W21t, B21, h1,  NN, 208, 64,  208, 208, 64);
    k_mm<1,false><<<dim3(2,157), 256, 0, stream>>>(h1,   W22t, B22, h2n, NN, 64,  128, 64,  64,  128);
    k_mm<0,false><<<dim3(4,157), 256, 0, stream>>>(h2n,  W23t, B23, m16, NN, 128, 256, 128, 128, 256);
    k_nodeup<<<dim3(4,157), 256, 0, stream>>>(nf16, m16, WLSt, WLNt, BLS, BLN, NF, nfu, nfu16);

    // ---- edge phase ----
    k_mm<0,false><<<dim3(6,157), 256, 0, stream>>>(nfu16, WE1n, nullptr, U1, NN, 256, 352, 256, 256, 352);
    k_mm<0,false><<<dim3(6,157), 256, 0, stream>>>(nfu16, W1n,  nullptr, U2, NN, 256, 352, 256, 256, 352);
    k_h2f<<<dim3(6, NE/64), 256, 0, stream>>>(ec16, U1, U2, src, dst, WE1e, BE1, W1e, B1, h2e);
    k_mm<1,false><<<dim3(3, NE/64), 256, 0, stream>>>(h2e, WE20t, BE20, e0b, NE, 352, 188, 352, 352, 192);
    k_mm<1,false><<<dim3(1, NE/64), 256, 0, stream>>>(e0b, WE21t, BE21, e1b, NE, 188, 24,  192, 192, 24);
    k_mm<1,false><<<dim3(1, NE/64), 256, 0, stream>>>(e1b, WE22t, BE22, e2b, NE, 24,  48,  24,  24,  48);
    k_mm<0,true ><<<dim3(2, NE/64), 256, 0, stream>>>(e2b, WE23t, BE23, efu, NE, 48,  96,  48,  48,  96);
}

// Round 13
// 678.103 us; speedup vs baseline: 9.6388x; 1.0700x over previous
//
#include <hip/hip_runtime.h>
#include <math.h>

#define NN 10000
#define NE 160000
#define DND 256
#define DER 64
#define DEA 32
#define DEC 96
#define DAC 352

typedef __attribute__((ext_vector_type(4))) float f32x4;
typedef __attribute__((ext_vector_type(8))) short bf16x8;

__device__ __forceinline__ float sigm(float x){ return 1.0f/(1.0f+__expf(-x)); }
__device__ __forceinline__ short f2b(float x){
    union { float f; unsigned u; } v; v.f = x;
    unsigned r = v.u + 0x7FFFu + ((v.u >> 16) & 1u);
    return (short)(r >> 16);
}
__device__ __forceinline__ float b2f(short s){
    union { float f; unsigned u; } v; v.u = ((unsigned)(unsigned short)s) << 16; return v.f;
}

// ---------------- s2[i] = src[src[i]] (reference quirk) ----------------
__global__ void k_s2(const int* __restrict__ src, int* __restrict__ s2){
    int i = blockIdx.x*256 + threadIdx.x;
    if (i < NE) s2[i] = src[src[i]];
}

// ---------------- dst histogram / scan / scatter (counting sort by dst) ----------------
__global__ void k_hist(const int* __restrict__ dst, int* __restrict__ cnt){
    int i = blockIdx.x*256 + threadIdx.x;
    if (i < NE) atomicAdd(&cnt[dst[i]], 1);
}
__global__ void k_scan(const int* __restrict__ cnt, int* __restrict__ cursor){
    __shared__ int sums[256];
    const int tid = threadIdx.x;
    const int CH = (NN + 255) / 256;            // 40
    int base = tid * CH, s = 0;
    for (int i = 0; i < CH; ++i){ int idx = base + i; if (idx < NN) s += cnt[idx]; }
    sums[tid] = s; __syncthreads();
    for (int off = 1; off < 256; off <<= 1){
        int t = (tid >= off) ? sums[tid - off] : 0;
        __syncthreads();
        sums[tid] += t;
        __syncthreads();
    }
    int run = sums[tid] - s;                    // exclusive base for this chunk
    for (int i = 0; i < CH; ++i){
        int idx = base + i;
        if (idx < NN){ cursor[idx] = run; run += cnt[idx]; }
    }
}
__global__ void k_scat(const int* __restrict__ dst, int* __restrict__ cursor,
                       int* __restrict__ perm){
    int i = blockIdx.x*256 + threadIdx.x;
    if (i < NE){ int p = atomicAdd(&cursor[dst[i]], 1); perm[p] = i; }
}

// ---------------- fused prep: nf16 + ec16 ----------------
__global__ void k_prep(const float* __restrict__ nf, const float* __restrict__ er,
                       const float* __restrict__ ea,
                       short* __restrict__ nf16, short* __restrict__ ec16){
    const int n1 = NN*DND, n2 = NE*DEC;
    int i = blockIdx.x*256 + threadIdx.x;
    int stride = gridDim.x*256;
    for (; i < n1 + n2; i += stride){
        if (i < n1) nf16[i] = f2b(nf[i]);
        else {
            int t = i - n1;
            int e = t / DEC, c = t - e*DEC;
            float v = (c < DER) ? er[(size_t)e*DER + c] : ea[(size_t)e*DEA + (c-DER)];
            ec16[t] = f2b(v);
        }
    }
}

// ---------------- f32 -> bf16 ----------------
__global__ void k_cvt(const float* __restrict__ in, short* __restrict__ out, int n){
    int i = blockIdx.x*256 + threadIdx.x;
    int stride = gridDim.x*256;
    for (; i < n; i += stride) out[i] = f2b(in[i]);
}

// ---------------- all weight transposes in one launch ----------------
struct WtJob { const float* W; long long dstOff; int K, N, ld, total; };
struct WtJobs { WtJob j[14]; int grand; };
__global__ void k_wtall(WtJobs jobs, short* __restrict__ pool){
    int i = blockIdx.x*256 + threadIdx.x;
    int stride = gridDim.x*256;
    for (; i < jobs.grand; i += stride){
        int t = i, jj = 0;
        while (t >= jobs.j[jj].total){ t -= jobs.j[jj].total; ++jj; }
        const WtJob J = jobs.j[jj];
        int n = t / J.ld, k = t - n*J.ld;
        pool[J.dstOff + t] = (k < J.K) ? f2b(J.W[(size_t)k*J.N + n]) : (short)0;
    }
}

// ---------------- MFMA helpers ----------------
__device__ __forceinline__ void stageB(short (*Bs)[40], const short* __restrict__ Wt,
                                       int col0, int N, int K, int ldW, int k0, int tid){
    int c = tid>>2, ks = tid&3, k = k0 + ks*8;
    bf16x8 v = {0,0,0,0,0,0,0,0};
    int gc = col0 + c;
    if (gc < N && k < K) v = *(const bf16x8*)&Wt[(size_t)gc*ldW + k];
    *(bf16x8*)&Bs[c][ks*8] = v;
}

__device__ __forceinline__ void mfma_step(const short (*As)[40], const short (*Bs)[40],
                                          int wm, int wn, int lane,
                                          f32x4& a00, f32x4& a01, f32x4& a10, f32x4& a11){
    const int kofs = (lane>>4)*8, lr = lane & 15;
    bf16x8 A0 = *(const bf16x8*)&As[wm*32 + lr][kofs];
    bf16x8 A1 = *(const bf16x8*)&As[wm*32 + 16 + lr][kofs];
    bf16x8 B0 = *(const bf16x8*)&Bs[wn*32 + lr][kofs];
    bf16x8 B1 = *(const bf16x8*)&Bs[wn*32 + 16 + lr][kofs];
    a00 = __builtin_amdgcn_mfma_f32_16x16x32_bf16(A0, B0, a00, 0, 0, 0);
    a01 = __builtin_amdgcn_mfma_f32_16x16x32_bf16(A0, B1, a01, 0, 0, 0);
    a10 = __builtin_amdgcn_mfma_f32_16x16x32_bf16(A1, B0, a10, 0, 0, 0);
    a11 = __builtin_amdgcn_mfma_f32_16x16x32_bf16(A1, B1, a11, 0, 0, 0);
}

// A from full-width LDS tile [64][104] (96 cols + pad), B from [64][40]
__device__ __forceinline__ void mfma_stepA(const short (*Af)[104], int k0,
                                           const short (*Bs)[40],
                                           int wm, int wn, int lane,
                                           f32x4& a00, f32x4& a01, f32x4& a10, f32x4& a11){
    const int kofs = (lane>>4)*8, lr = lane & 15;
    bf16x8 A0 = *(const bf16x8*)&Af[wm*32 + lr][k0 + kofs];
    bf16x8 A1 = *(const bf16x8*)&Af[wm*32 + 16 + lr][k0 + kofs];
    bf16x8 B0 = *(const bf16x8*)&Bs[wn*32 + lr][kofs];
    bf16x8 B1 = *(const bf16x8*)&Bs[wn*32 + 16 + lr][kofs];
    a00 = __builtin_amdgcn_mfma_f32_16x16x32_bf16(A0, B0, a00, 0, 0, 0);
    a01 = __builtin_amdgcn_mfma_f32_16x16x32_bf16(A0, B1, a01, 0, 0, 0);
    a10 = __builtin_amdgcn_mfma_f32_16x16x32_bf16(A1, B0, a10, 0, 0, 0);
    a11 = __builtin_amdgcn_mfma_f32_16x16x32_bf16(A1, B1, a11, 0, 0, 0);
}

// direct K-loop, K = 256 (node matrices)
__device__ __forceinline__ void gemm_direct256(const short* __restrict__ A, int row0,
    const short* __restrict__ Wt, int col0, int tid, int lane, int wm, int wn,
    short (*As)[40], short (*Bs)[40],
    f32x4& a00, f32x4& a01, f32x4& a10, f32x4& a11)
{
    for (int k0 = 0; k0 < DND; k0 += 32){
        {
            int r = tid>>2, ks = tid&3, k = k0 + ks*8;
            bf16x8 v = {0,0,0,0,0,0,0,0};
            int gr = row0 + r;
            if (gr < NN) v = *(const bf16x8*)&A[(size_t)gr*DND + k];
            *(bf16x8*)&As[r][ks*8] = v;
        }
        stageB(Bs, Wt, col0, DND, DND, DND, k0, tid);
        __syncthreads();
        mfma_step(As, Bs, wm, wn, lane, a00, a01, a10, a11);
        __syncthreads();
    }
}

// ---------------- generic C = act(A@Wt^T + b) ----------------
template<int ACT, bool F32OUT>   // ACT: 0 none, 1 relu
__global__ __launch_bounds__(256) void k_mm(const short* __restrict__ A,
                      const short* __restrict__ Wt, const float* __restrict__ bias,
                      void* __restrict__ Cv,
                      int M, int K, int N, int ldA, int ldW, int ldC)
{
    __shared__ short As[64][40];
    __shared__ short Bs[64][40];
    const int tid = threadIdx.x, lane = tid & 63, wave = tid >> 6;
    const int wm = wave >> 1, wn = wave & 1;
    const int row0 = blockIdx.y << 6, col0 = blockIdx.x << 6;
    f32x4 a00={0,0,0,0}, a01={0,0,0,0}, a10={0,0,0,0}, a11={0,0,0,0};
    for (int k0 = 0; k0 < K; k0 += 32){
        {
            int r = tid>>2, ks = tid&3, k = k0 + ks*8;
            bf16x8 v = {0,0,0,0,0,0,0,0};
            int gr = row0 + r;
            if (gr < M && k < K) v = *(const bf16x8*)&A[(size_t)gr*ldA + k];
            *(bf16x8*)&As[r][ks*8] = v;
        }
        stageB(Bs, Wt, col0, N, K, ldW, k0, tid);
        __syncthreads();
        mfma_step(As, Bs, wm, wn, lane, a00, a01, a10, a11);
        __syncthreads();
    }
    const int lr = lane & 15, lq = lane >> 4;
    f32x4 accs[2][2] = {{a00,a01},{a10,a11}};
    #pragma unroll
    for (int i = 0; i < 2; ++i)
      #pragma unroll
      for (int j = 0; j < 2; ++j){
        int col = col0 + wn*32 + j*16 + lr;
        if (col >= ldC) continue;
        bool valid = col < N;
        float bs = (valid && bias) ? bias[col] : 0.f;
        #pragma unroll
        for (int q = 0; q < 4; ++q){
            int row = row0 + wm*32 + i*16 + lq*4 + q;
            if (row >= M) continue;
            float v = valid ? (accs[i][j][q] + bs) : 0.f;
            if (ACT == 1) v = fmaxf(v, 0.f);
            if (F32OUT) ((float*)Cv)[(size_t)row*ldC + col] = v;
            else        ((short*)Cv)[(size_t)row*ldC + col] = f2b(v);
        }
      }
}

// ------- msg (dst-sorted, col-loop): sigm(V16[s2[perm]] + ec[perm]@W1e + b1) -> segmented agg -------
__global__ __launch_bounds__(256) void k_msga(const short* __restrict__ ec16,
                       const short* __restrict__ V16,
                       const int* __restrict__ perm,
                       const int* __restrict__ s2, const int* __restrict__ dst,
                       const short* __restrict__ WeT, const float* __restrict__ b1,
                       float* __restrict__ agg)
{
    __shared__ short Af[64][104];
    __shared__ short Bs[64][40];
    __shared__ float vals[64][65];
    __shared__ int pe[64], ss[64], dd[64];
    const int tid = threadIdx.x, lane = tid & 63, wave = tid >> 6;
    const int wm = wave >> 1, wn = wave & 1;
    const int e0 = blockIdx.x << 6;
    if (tid < 64){
        int e = perm[e0 + tid];
        pe[tid] = e; ss[tid] = s2[e]; dd[tid] = dst[e];
    }
    __syncthreads();
    // stage full 64x96 ec tile once (768 bf16x8 chunks, 3 per thread)
    #pragma unroll
    for (int l = 0; l < 3; ++l){
        int c = tid + (l << 8);
        int r = c / 12, kk = c - r*12;
        *(bf16x8*)&Af[r][kk*8] = *(const bf16x8*)&ec16[(size_t)pe[r]*DEC + kk*8];
    }
    const int lr = lane & 15, lq = lane >> 4;
    for (int cb = 0; cb < 6; ++cb){
        const int col0 = cb << 6;
        f32x4 a00={0,0,0,0}, a01={0,0,0,0}, a10={0,0,0,0}, a11={0,0,0,0};
        for (int k0 = 0; k0 < DEC; k0 += 32){
            stageB(Bs, WeT, col0, DAC, DEC, DEC, k0, tid);
            __syncthreads();
            mfma_stepA(Af, k0, Bs, wm, wn, lane, a00, a01, a10, a11);
            __syncthreads();
        }
        f32x4 accs[2][2] = {{a00,a01},{a10,a11}};
        #pragma unroll
        for (int i = 0; i < 2; ++i)
          #pragma unroll
          for (int j = 0; j < 2; ++j){
            int cl = wn*32 + j*16 + lr;
            int gc = col0 + cl;
            float bs = (gc < DAC) ? b1[gc] : 0.f;
            #pragma unroll
            for (int q = 0; q < 4; ++q){
                int rl = wm*32 + i*16 + lq*4 + q;
                float v = 0.f;
                if (gc < DAC)
                    v = sigm(accs[i][j][q] + b2f(V16[(size_t)ss[rl]*DAC + gc]) + bs);
                vals[rl][cl] = v;
            }
          }
        __syncthreads();
        // segmented (run-length) reduction over dst-sorted rows
        int c = tid & 63, gc2 = col0 + c;
        if (gc2 < DAC){
            int r0 = (tid >> 6) * 16;
            float run = vals[r0][c]; int cur = dd[r0];
            #pragma unroll
            for (int r = r0 + 1; r < r0 + 16; ++r){
                int n = dd[r]; float v = vals[r][c];
                if (n == cur) run += v;
                else { atomicAdd(&agg[(size_t)cur*DAC + gc2], run); cur = n; run = v; }
            }
            atomicAdd(&agg[(size_t)cur*DAC + gc2], run);
        }
        __syncthreads();
    }
}

// ------- h2 (col-loop) = sigm(U1[src]+ec@WE1e+be1) + sigm(U2[dst]+ec@W1e+b1) -> bf16 -------
__global__ __launch_bounds__(256) void k_h2g(const short* __restrict__ ec16,
                       const short* __restrict__ U1, const short* __restrict__ U2,
                       const int* __restrict__ src, const int* __restrict__ dst,
                       const short* __restrict__ WsT, const float* __restrict__ bsv,
                       const short* __restrict__ WtT, const float* __restrict__ btv,
                       short* __restrict__ h2)
{
    __shared__ short Af[64][104];
    __shared__ short B1s[64][40];
    __shared__ short B2s[64][40];
    __shared__ int ss[64], dd[64];
    const int tid = threadIdx.x, lane = tid & 63, wave = tid >> 6;
    const int wm = wave >> 1, wn = wave & 1;
    const int e0 = blockIdx.x << 6;
    if (tid < 64){ ss[tid] = src[e0+tid]; dd[tid] = dst[e0+tid]; }
    #pragma unroll
    for (int l = 0; l < 3; ++l){
        int c = tid + (l << 8);
        int r = c / 12, kk = c - r*12;
        *(bf16x8*)&Af[r][kk*8] = *(const bf16x8*)&ec16[(size_t)(e0+r)*DEC + kk*8];
    }
    const int lr = lane & 15, lq = lane >> 4;
    for (int cb = 0; cb < 6; ++cb){
        const int col0 = cb << 6;
        f32x4 s00={0,0,0,0}, s01={0,0,0,0}, s10={0,0,0,0}, s11={0,0,0,0};
        f32x4 t00={0,0,0,0}, t01={0,0,0,0}, t10={0,0,0,0}, t11={0,0,0,0};
        for (int k0 = 0; k0 < DEC; k0 += 32){
            stageB(B1s, WsT, col0, DAC, DEC, DEC, k0, tid);
            stageB(B2s, WtT, col0, DAC, DEC, DEC, k0, tid);
            __syncthreads();
            mfma_stepA(Af, k0, B1s, wm, wn, lane, s00, s01, s10, s11);
            mfma_stepA(Af, k0, B2s, wm, wn, lane, t00, t01, t10, t11);
            __syncthreads();
        }
        f32x4 sa[2][2] = {{s00,s01},{s10,s11}};
        f32x4 ta[2][2] = {{t00,t01},{t10,t11}};
        #pragma unroll
        for (int i = 0; i < 2; ++i)
          #pragma unroll
          for (int j = 0; j < 2; ++j){
            int col = col0 + wn*32 + j*16 + lr;
            if (col >= DAC) continue;
            float cbs = bsv[col], cbt = btv[col];
            #pragma unroll
            for (int q = 0; q < 4; ++q){
                int rl = wm*32 + i*16 + lq*4 + q;
                float v = sigm(sa[i][j][q] + b2f(U1[(size_t)ss[rl]*DAC + col]) + cbs)
                        + sigm(ta[i][j][q] + b2f(U2[(size_t)dd[rl]*DAC + col]) + cbt);
                h2[(size_t)(e0+rl)*DAC + col] = f2b(v);
            }
          }
    }
}

// ---------------- node update ----------------
__global__ __launch_bounds__(256) void k_nodeup(const short* __restrict__ nf16,
                       const short* __restrict__ m16,
                       const short* __restrict__ Wlst, const short* __restrict__ Wlnt,
                       const float* __restrict__ bls, const float* __restrict__ bln,
                       const float* __restrict__ nf, float* __restrict__ nfu,
                       short* __restrict__ nfu16)
{
    __shared__ short As[64][40];
    __shared__ short Bs[64][40];
    const int tid = threadIdx.x, lane = tid & 63, wave = tid >> 6;
    const int wm = wave >> 1, wn = wave & 1;
    const int row0 = blockIdx.y << 6, col0 = blockIdx.x << 6;
    f32x4 s00={0,0,0,0}, s01={0,0,0,0}, s10={0,0,0,0}, s11={0,0,0,0};
    f32x4 t00={0,0,0,0}, t01={0,0,0,0}, t10={0,0,0,0}, t11={0,0,0,0};
    gemm_direct256(nf16, row0, Wlst, col0, tid, lane, wm, wn, As, Bs, s00,s01,s10,s11);
    gemm_direct256(m16,  row0, Wlnt, col0, tid, lane, wm, wn, As, Bs, t00,t01,t10,t11);
    const int lr = lane & 15, lq = lane >> 4;
    f32x4 sa[2][2] = {{s00,s01},{s10,s11}};
    f32x4 ta[2][2] = {{t00,t01},{t10,t11}};
    #pragma unroll
    for (int i = 0; i < 2; ++i)
      #pragma unroll
      for (int j = 0; j < 2; ++j){
        int col = col0 + wn*32 + j*16 + lr;
        float bb = bls[col] + bln[col];
        #pragma unroll
        for (int q = 0; q < 4; ++q){
            int row = row0 + wm*32 + i*16 + lq*4 + q;
            if (row >= NN) continue;
            float v = sigm(sa[i][j][q] + ta[i][j][q] + bb) + nf[(size_t)row*DND + col];
            nfu[(size_t)row*DND + col] = v;
            nfu16[(size_t)row*DND + col] = f2b(v);
        }
      }
}

extern "C" void kernel_launch(void* const* d_in, const int* in_sizes, int n_in,
                              void* d_out, int out_size, void* d_ws, size_t ws_size,
                              hipStream_t stream)
{
    const float* NF  = (const float*)d_in[0];
    const float* ERD = (const float*)d_in[1];
    const float* EAD = (const float*)d_in[2];
    const int*   EIX = (const int*)d_in[3];
    const int* src = EIX; const int* dst = EIX + NE;
    const float* W1   = (const float*)d_in[4];  const float* B1   = (const float*)d_in[5];
    const float* W20  = (const float*)d_in[6];  const float* B20  = (const float*)d_in[7];
    const float* W21  = (const float*)d_in[8];  const float* B21  = (const float*)d_in[9];
    const float* W22  = (const float*)d_in[10]; const float* B22  = (const float*)d_in[11];
    const float* W23  = (const float*)d_in[12]; const float* B23  = (const float*)d_in[13];
    const float* WLS  = (const float*)d_in[14]; const float* BLS  = (const float*)d_in[15];
    const float* WLN  = (const float*)d_in[16]; const float* BLN  = (const float*)d_in[17];
    const float* WE1  = (const float*)d_in[18]; const float* BE1  = (const float*)d_in[19];
    const float* WE20 = (const float*)d_in[20]; const float* BE20 = (const float*)d_in[21];
    const float* WE21 = (const float*)d_in[22]; const float* BE21 = (const float*)d_in[23];
    const float* WE22 = (const float*)d_in[24]; const float* BE22 = (const float*)d_in[25];
    const float* WE23 = (const float*)d_in[26]; const float* BE23 = (const float*)d_in[27];

    float* nfu = (float*)d_out;
    float* efu = nfu + (size_t)NN*DND;

    char* p = (char*)d_ws;
    auto alloc = [&](size_t bytes)->char*{ char* q = p; p += (bytes + 255) & ~(size_t)255; return q; };
    // persistent
    int*   s2    = (int*)  alloc((size_t)NE*4);
    int*   perm  = (int*)  alloc((size_t)NE*4);
    int*   cnt   = (int*)  alloc((size_t)NN*4);
    int*   cursor= (int*)  alloc((size_t)NN*4);
    short* nf16  = (short*)alloc((size_t)NN*DND*2);
    short* ec16  = (short*)alloc((size_t)NE*DEC*2);
    short* nfu16 = (short*)alloc((size_t)NN*DND*2);
    short* wpool = (short*)alloc((size_t)600000*2);
    // slabA: node-phase scratch, later reused for U1/U2 (bf16)
    char*  slabA = alloc((size_t)36*1024*1024);
    float* agg   = (float*)slabA;                               // [NN*352] f32 (14.08 MB)
    short* V16   = (short*)(slabA + (size_t)NN*DAC*4);          // [NN*352] bf16 (7.04 MB)
    short* agg16 = V16;                                         // aliases V16 (V16 dead after k_msga)
    short* h0    = (short*)((char*)V16 + (size_t)NN*DAC*2);     // [NN*208]
    short* h1    = (short*)((char*)h0 + (size_t)NN*208*2);      // [NN*64]
    short* h2n   = (short*)((char*)h1 + (size_t)NN*64*2);       // [NN*128]
    short* m16   = (short*)((char*)h2n + (size_t)NN*128*2);     // [NN*256]
    short* U1    = (short*)slabA;                               // agg dead in edge phase
    short* U2    = (short*)(slabA + (size_t)NN*DAC*2);
    // slabB: edge-phase
    short* h2e   = (short*)alloc((size_t)NE*DAC*2);             // 112.6 MB
    short* e0b   = (short*)alloc((size_t)NE*192*2);             // 61.4 MB
    short* e1b   = (short*)h2e;                                 // aliases h2e (dead after e0b GEMM)
    short* e2b   = (short*)((char*)h2e + (size_t)8*1024*1024);

    // weight pool offsets (elements)
    long long off = 0; WtJobs jobs; int nj = 0;
    auto addjob = [&](const float* W, int K, int N, int ld)->long long{
        long long o = off;
        jobs.j[nj] = { W, o, K, N, ld, N*ld };
        off += (long long)N*ld; ++nj; return o;
    };
    short* W1n  = wpool + addjob(W1,            256, 352, 256);
    short* W1e  = wpool + addjob(W1 + 256*352,   96, 352,  96);
    short* WE1n = wpool + addjob(WE1,           256, 352, 256);
    short* WE1e = wpool + addjob(WE1 + 256*352,  96, 352,  96);
    short* W20t = wpool + addjob(W20, 352, 208, 352);
    short* W21t = wpool + addjob(W21, 208,  64, 208);
    short* W22t = wpool + addjob(W22,  64, 128,  64);
    short* W23t = wpool + addjob(W23, 128, 256, 128);
    short* WLSt = wpool + addjob(WLS, 256, 256, 256);
    short* WLNt = wpool + addjob(WLN, 256, 256, 256);
    short* WE20t= wpool + addjob(WE20, 352, 188, 352);
    short* WE21t= wpool + addjob(WE21, 188,  24, 192);
    short* WE22t= wpool + addjob(WE22,  24,  48,  24);
    short* WE23t= wpool + addjob(WE23,  48,  96,  48);
    jobs.grand = (int)off;

    // ---- prep ----
    k_s2  <<<dim3((NE+255)/256), 256, 0, stream>>>(src, s2);
    hipMemsetAsync(cnt, 0, (size_t)NN*4, stream);
    k_hist<<<dim3((NE+255)/256), 256, 0, stream>>>(dst, cnt);
    k_scan<<<dim3(1), 256, 0, stream>>>(cnt, cursor);
    k_scat<<<dim3((NE+255)/256), 256, 0, stream>>>(dst, cursor, perm);
    k_prep<<<dim3(2048), 256, 0, stream>>>(NF, ERD, EAD, nf16, ec16);
    k_wtall<<<dim3((jobs.grand+255)/256), 256, 0, stream>>>(jobs, wpool);

    // ---- node phase ----
    k_mm<0,false><<<dim3(6,157), 256, 0, stream>>>(nf16, W1n, nullptr, V16, NN, 256, 352, 256, 256, 352);
    hipMemsetAsync(agg, 0, sizeof(float)*(size_t)NN*DAC, stream);
    k_msga<<<dim3(NE/64), 256, 0, stream>>>(ec16, V16, perm, s2, dst, W1e, B1, agg);
    k_cvt<<<dim3(2048), 256, 0, stream>>>(agg, agg16, NN*DAC);
    k_mm<1,false><<<dim3(4,157), 256, 0, stream>>>(agg16, W20t, B20, h0,  NN, 352, 208, 352, 352, 208);
    k_mm<1,false><<<dim3(1,157), 256, 0, stream>>>(h0,   W21t, B21, h1,  NN, 208, 64,  208, 208, 64);
    k_mm<1,false><<<dim3(2,157), 256, 0, stream>>>(h1,   W22t, B22, h2n, NN, 64,  128, 64,  64,  128);
    k_mm<0,false><<<dim3(4,157), 256, 0, stream>>>(h2n,  W23t, B23, m16, NN, 128, 256, 128, 128, 256);
    k_nodeup<<<dim3(4,157), 256, 0, stream>>>(nf16, m16, WLSt, WLNt, BLS, BLN, NF, nfu, nfu16);

    // ---- edge phase ----
    k_mm<0,false><<<dim3(6,157), 256, 0, stream>>>(nfu16, WE1n, nullptr, U1, NN, 256, 352, 256, 256, 352);
    k_mm<0,false><<<dim3(6,157), 256, 0, stream>>>(nfu16, W1n,  nullptr, U2, NN, 256, 352, 256, 256, 352);
    k_h2g<<<dim3(NE/64), 256, 0, stream>>>(ec16, U1, U2, src, dst, WE1e, BE1, W1e, B1, h2e);
    k_mm<1,false><<<dim3(3, NE/64), 256, 0, stream>>>(h2e, WE20t, BE20, e0b, NE, 352, 188, 352, 352, 192);
    k_mm<1,false><<<dim3(1, NE/64), 256, 0, stream>>>(e0b, WE21t, BE21, e1b, NE, 188, 24,  192, 192, 24);
    k_mm<1,false><<<dim3(1, NE/64), 256, 0, stream>>>(e1b, WE22t, BE22, e2b, NE, 24,  48,  24,  24,  48);
    k_mm<0,true ><<<dim3(2, NE/64), 256, 0, stream>>>(e2b, WE23t, BE23, efu, NE, 48,  96,  48,  48,  96);
}